// Round 1
// baseline (1898.858 us; speedup 1.0000x reference)
//
#include <hip/hip_runtime.h>
#include <math.h>

#define HW 16384
#define WD 128
#define HD 128
#define CIN 64
#define CH 128
#define EPSV 1e-5f

// ---------------------------------------------------------------------------
// Kernel 1: feat = LayerNorm_c(conv1x1(x, conv_w))  for both images (blockIdx.z)
// Two-pass over output channels to keep VGPR use at ~70 (xv[64] + temps).
// ---------------------------------------------------------------------------
__global__ __launch_bounds__(256) void k_feat(const float* __restrict__ rgb,
                                              const float* __restrict__ ev,
                                              const float* __restrict__ cw,   // [128][64]
                                              const float* __restrict__ g,
                                              const float* __restrict__ b,
                                              float* __restrict__ feat_rgb,
                                              float* __restrict__ feat_ev) {
  __shared__ __align__(16) float swt[CH * CIN];   // 32 KB
  __shared__ float sg[CH], sb[CH];
  int tid = threadIdx.x;
  for (int i = tid; i < CH * CIN; i += 256) swt[i] = cw[i];
  if (tid < CH) { sg[tid] = g[tid]; sb[tid] = b[tid]; }
  __syncthreads();
  const float* x = blockIdx.z ? ev : rgb;
  float* feat = blockIdx.z ? feat_ev : feat_rgb;
  int p = blockIdx.x * 256 + tid;

  float xv[CIN];
#pragma unroll
  for (int i = 0; i < CIN; ++i) xv[i] = x[i * HW + p];

  float s = 0.f, s2 = 0.f;
  for (int o = 0; o < CH; ++o) {
    float a0 = 0.f, a1 = 0.f, a2 = 0.f, a3 = 0.f;
#pragma unroll
    for (int i = 0; i < CIN; i += 4) {
      a0 += swt[o * CIN + i]     * xv[i];
      a1 += swt[o * CIN + i + 1] * xv[i + 1];
      a2 += swt[o * CIN + i + 2] * xv[i + 2];
      a3 += swt[o * CIN + i + 3] * xv[i + 3];
    }
    float acc = (a0 + a1) + (a2 + a3);
    s += acc; s2 += acc * acc;
  }
  float mean = s * (1.f / CH);
  float var = s2 * (1.f / CH) - mean * mean;
  float rinv = rsqrtf(var + EPSV);
  for (int o = 0; o < CH; ++o) {
    float a0 = 0.f, a1 = 0.f, a2 = 0.f, a3 = 0.f;
#pragma unroll
    for (int i = 0; i < CIN; i += 4) {
      a0 += swt[o * CIN + i]     * xv[i];
      a1 += swt[o * CIN + i + 1] * xv[i + 1];
      a2 += swt[o * CIN + i + 2] * xv[i + 2];
      a3 += swt[o * CIN + i + 3] * xv[i + 3];
    }
    float acc = (a0 + a1) + (a2 + a3);
    feat[o * HW + p] = (acc - mean) * rinv * sg[o] + sb[o];
  }
}

// ---------------------------------------------------------------------------
// Kernel 2: r = relu(conv3x3(feat, df1_w)).  Block = 256 px (2 rows) x 8 m.
// Weights staged transposed in LDS as [c][tap][8m] -> 2x float4 broadcast.
// ---------------------------------------------------------------------------
__global__ __launch_bounds__(256) void k_conv3(const float* __restrict__ feat_rgb,
                                               const float* __restrict__ feat_ev,
                                               const float* __restrict__ w3,  // [128][128][3][3]
                                               float* __restrict__ r_rgb,
                                               float* __restrict__ r_ev) {
  __shared__ __align__(16) float wl[CH * 9 * 8];  // 36 KB
  int tid = threadIdx.x;
  int mb = blockIdx.y;  // 0..15, 8 m each
  for (int i = tid; i < CH * 9 * 8; i += 256) {
    int mi = i & 7;
    int tap = (i >> 3) % 9;
    int c = i / 72;
    wl[i] = w3[((mb * 8 + mi) * CH + c) * 9 + tap];
  }
  __syncthreads();
  const float* feat = blockIdx.z ? feat_ev : feat_rgb;
  float* r = blockIdx.z ? r_ev : r_rgb;
  int strip = blockIdx.x;  // 2 rows per strip
  int ty = tid >> 7;
  int tx = tid & 127;
  int h = strip * 2 + ty;
  float acc[8];
#pragma unroll
  for (int mi = 0; mi < 8; ++mi) acc[mi] = 0.f;
  bool up_ok = h > 0, dn_ok = h < HD - 1;
  bool lf_ok = tx > 0, rt_ok = tx < WD - 1;
  for (int c = 0; c < CH; ++c) {
    const float* fb = feat + c * HW + h * WD + tx;
    float f[9];
    f[0] = (up_ok && lf_ok) ? fb[-WD - 1] : 0.f;
    f[1] = up_ok ? fb[-WD] : 0.f;
    f[2] = (up_ok && rt_ok) ? fb[-WD + 1] : 0.f;
    f[3] = lf_ok ? fb[-1] : 0.f;
    f[4] = fb[0];
    f[5] = rt_ok ? fb[1] : 0.f;
    f[6] = (dn_ok && lf_ok) ? fb[WD - 1] : 0.f;
    f[7] = dn_ok ? fb[WD] : 0.f;
    f[8] = (dn_ok && rt_ok) ? fb[WD + 1] : 0.f;
#pragma unroll
    for (int tap = 0; tap < 9; ++tap) {
      const float4* wp = (const float4*)&wl[(c * 9 + tap) * 8];
      float4 w0 = wp[0], w1 = wp[1];
      acc[0] += w0.x * f[tap]; acc[1] += w0.y * f[tap];
      acc[2] += w0.z * f[tap]; acc[3] += w0.w * f[tap];
      acc[4] += w1.x * f[tap]; acc[5] += w1.y * f[tap];
      acc[6] += w1.z * f[tap]; acc[7] += w1.w * f[tap];
    }
  }
  int p = h * WD + tx;
#pragma unroll
  for (int mi = 0; mi < 8; ++mi) r[(mb * 8 + mi) * HW + p] = fmaxf(acc[mi], 0.f);
}

// ---------------------------------------------------------------------------
// Kernel 3 (dominant): fused dynamic-filter generation + apply.
//   filt[c*25+t](p) = dot(df2[c*25+t][:], r[:, p])   (never materialized)
//   en[c](p) = sum_t featwin[c][t-offset] * filt
// Block = 4x4 pixel tile x 16 c-groups.  tid = tg*16 + pxl so each wave has
// only 4 distinct df2 rows in flight (L1 broadcast).  r_vec in 128 VGPRs.
// ---------------------------------------------------------------------------
__global__ __launch_bounds__(256) void k_filt(
    const float* __restrict__ feat_rgb, const float* __restrict__ feat_ev,
    const float* __restrict__ r_rgb, const float* __restrict__ r_ev,
    const float* __restrict__ df2,   // [3200][128]
    float* __restrict__ en_rgb, float* __restrict__ en_ev) {
  __shared__ __align__(16) float fw[CH * 64];    // 32 KB feat window [c][8][8]
  __shared__ __align__(16) float rl[16 * 132];   // 8.25 KB (pad 132 kills conflicts)
  const float* feat = blockIdx.z ? feat_ev : feat_rgb;
  const float* r = blockIdx.z ? r_ev : r_rgb;
  float* en = blockIdx.z ? en_ev : en_rgb;
  int tid = threadIdx.x;
  int Rr = blockIdx.y * 4, Cc = blockIdx.x * 4;

  // stage feat window with zero-pad (rows Rr-2..Rr+5, cols Cc-2..Cc+5)
  for (int i = tid; i < CH * 64; i += 256) {
    int c = i >> 6, wr = (i >> 3) & 7, wc = i & 7;
    int h = Rr + wr - 2, w = Cc + wc - 2;
    fw[i] = (h >= 0 && h < HD && w >= 0 && w < WD) ? feat[c * HW + h * WD + w] : 0.f;
  }
  // stage r for the 16 tile pixels
  for (int i = tid; i < 2048; i += 256) {
    int pxl = i & 15, m = i >> 4;
    int h = Rr + (pxl >> 2), w = Cc + (pxl & 3);
    rl[pxl * 132 + m] = r[m * HW + h * WD + w];
  }
  __syncthreads();

  int tg = tid >> 4, pxl = tid & 15;
  int pr = pxl >> 2, pc = pxl & 3;
  int p = (Rr + pr) * WD + (Cc + pc);

  float4 rv[32];
#pragma unroll
  for (int q = 0; q < 32; ++q) rv[q] = *(const float4*)&rl[pxl * 132 + q * 4];

  for (int ci = 0; ci < 8; ++ci) {
    int c = tg * 8 + ci;
    float acc = 0.f;
    for (int t = 0; t < 25; ++t) {
      const float4* dw = (const float4*)(df2 + (c * 25 + t) * CH);
      float f0 = 0.f, f1 = 0.f, f2 = 0.f, f3 = 0.f;
#pragma unroll
      for (int q = 0; q < 32; ++q) {
        float4 wq = dw[q];
        f0 += wq.x * rv[q].x; f1 += wq.y * rv[q].y;
        f2 += wq.z * rv[q].z; f3 += wq.w * rv[q].w;
      }
      float fs = (f0 + f1) + (f2 + f3);
      acc += fw[c * 64 + (pr + t / 5) * 8 + (pc + t % 5)] * fs;
    }
    en[c * HW + p] = acc;
  }
}

// ---------------------------------------------------------------------------
// Kernel 4: fused = en_rgb * (1 + sigmoid(sp_w @ en_ev)) + feat_rgb
// ---------------------------------------------------------------------------
__global__ __launch_bounds__(256) void k_fuse(
    const float* __restrict__ en_rgb, const float* __restrict__ en_ev,
    const float* __restrict__ feat_rgb, const float* __restrict__ sp_w,
    float* __restrict__ fused) {
  __shared__ __align__(16) float sw[CH * CH];  // 64 KB
  int tid = threadIdx.x;
  for (int i = tid; i < CH * CH; i += 256) sw[i] = sp_w[i];
  __syncthreads();
  int p = blockIdx.x * 256 + tid;
  float evv[CH];
#pragma unroll
  for (int i = 0; i < CH; ++i) evv[i] = en_ev[i * HW + p];
  for (int o = 0; o < CH; ++o) {
    float a0 = 0.f, a1 = 0.f, a2 = 0.f, a3 = 0.f;
#pragma unroll
    for (int i = 0; i < CH; i += 4) {
      a0 += sw[o * CH + i]     * evv[i];
      a1 += sw[o * CH + i + 1] * evv[i + 1];
      a2 += sw[o * CH + i + 2] * evv[i + 2];
      a3 += sw[o * CH + i + 3] * evv[i + 3];
    }
    float z = (a0 + a1) + (a2 + a3);
    float sg = 1.f / (1.f + __expf(-z));
    fused[o * HW + p] = en_rgb[o * HW + p] * (1.f + sg) + feat_rgb[o * HW + p];
  }
}

// ---------------------------------------------------------------------------
// Kernel 5: out = out_w @ LayerNorm_c(fused)
// ---------------------------------------------------------------------------
__global__ __launch_bounds__(256) void k_out(
    const float* __restrict__ fused, const float* __restrict__ g,
    const float* __restrict__ b, const float* __restrict__ out_w,
    float* __restrict__ out) {
  __shared__ __align__(16) float sw[64 * CH];  // 32 KB
  __shared__ float sg[CH], sb[CH];
  int tid = threadIdx.x;
  for (int i = tid; i < 64 * CH; i += 256) sw[i] = out_w[i];
  if (tid < CH) { sg[tid] = g[tid]; sb[tid] = b[tid]; }
  __syncthreads();
  int p = blockIdx.x * 256 + tid;
  float v[CH];
  float s = 0.f, s2 = 0.f;
#pragma unroll
  for (int i = 0; i < CH; ++i) {
    v[i] = fused[i * HW + p];
    s += v[i]; s2 += v[i] * v[i];
  }
  float mean = s * (1.f / CH), var = s2 * (1.f / CH) - mean * mean;
  float rinv = rsqrtf(var + EPSV);
#pragma unroll
  for (int i = 0; i < CH; ++i) v[i] = (v[i] - mean) * rinv * sg[i] + sb[i];
  for (int q = 0; q < 64; ++q) {
    float a0 = 0.f, a1 = 0.f, a2 = 0.f, a3 = 0.f;
#pragma unroll
    for (int i = 0; i < CH; i += 4) {
      a0 += sw[q * CH + i]     * v[i];
      a1 += sw[q * CH + i + 1] * v[i + 1];
      a2 += sw[q * CH + i + 2] * v[i + 2];
      a3 += sw[q * CH + i + 3] * v[i + 3];
    }
    out[q * HW + p] = (a0 + a1) + (a2 + a3);
  }
}

extern "C" void kernel_launch(void* const* d_in, const int* in_sizes, int n_in,
                              void* d_out, int out_size, void* d_ws, size_t ws_size,
                              hipStream_t stream) {
  const float* rgb  = (const float*)d_in[0];
  const float* ev   = (const float*)d_in[1];
  const float* cw   = (const float*)d_in[2];
  const float* g    = (const float*)d_in[3];
  const float* b    = (const float*)d_in[4];
  const float* w3   = (const float*)d_in[5];
  const float* df2  = (const float*)d_in[6];
  const float* spw  = (const float*)d_in[7];
  const float* outw = (const float*)d_in[8];
  float* out = (float*)d_out;
  float* ws = (float*)d_ws;

  // workspace layout (floats): 6 buffers x 2,097,152 = 48 MB total
  float* feat_rgb = ws;
  float* feat_ev  = ws + 1 * 2097152;
  float* r_rgb    = ws + 2 * 2097152;
  float* r_ev     = ws + 3 * 2097152;
  float* en_rgb   = ws + 4 * 2097152;
  float* en_ev    = ws + 5 * 2097152;
  float* fused    = r_rgb;  // reuse (r_* dead after k_filt)

  hipLaunchKernelGGL(k_feat, dim3(64, 1, 2), dim3(256), 0, stream,
                     rgb, ev, cw, g, b, feat_rgb, feat_ev);
  hipLaunchKernelGGL(k_conv3, dim3(64, 16, 2), dim3(256), 0, stream,
                     feat_rgb, feat_ev, w3, r_rgb, r_ev);
  hipLaunchKernelGGL(k_filt, dim3(32, 32, 2), dim3(256), 0, stream,
                     feat_rgb, feat_ev, r_rgb, r_ev, df2, en_rgb, en_ev);
  hipLaunchKernelGGL(k_fuse, dim3(64), dim3(256), 0, stream,
                     en_rgb, en_ev, feat_rgb, spw, fused);
  hipLaunchKernelGGL(k_out, dim3(64), dim3(256), 0, stream,
                     fused, g, b, outw, out);
}

// Round 2
// 500.073 us; speedup vs baseline: 3.7972x; 3.7972x over previous
//
#include <hip/hip_runtime.h>
#include <math.h>

#define HW 16384
#define WD 128
#define HD 128
#define CIN 64
#define CH 128
#define EPSV 1e-5f

typedef __attribute__((ext_vector_type(8))) short short8;
typedef __attribute__((ext_vector_type(4))) float f32x4;

__device__ __forceinline__ short f2bf(float x) {
  unsigned u = __float_as_uint(x);
  u += 0x7FFFu + ((u >> 16) & 1u);   // RNE
  return (short)(u >> 16);
}

// ---------------------------------------------------------------------------
// Kernel 1: feat = LayerNorm_c(conv1x1(x, conv_w))  for both images (blockIdx.z)
// ---------------------------------------------------------------------------
__global__ __launch_bounds__(256) void k_feat(const float* __restrict__ rgb,
                                              const float* __restrict__ ev,
                                              const float* __restrict__ cw,   // [128][64]
                                              const float* __restrict__ g,
                                              const float* __restrict__ b,
                                              float* __restrict__ feat_rgb,
                                              float* __restrict__ feat_ev) {
  __shared__ __align__(16) float swt[CH * CIN];   // 32 KB
  __shared__ float sg[CH], sb[CH];
  int tid = threadIdx.x;
  for (int i = tid; i < CH * CIN; i += 256) swt[i] = cw[i];
  if (tid < CH) { sg[tid] = g[tid]; sb[tid] = b[tid]; }
  __syncthreads();
  const float* x = blockIdx.z ? ev : rgb;
  float* feat = blockIdx.z ? feat_ev : feat_rgb;
  int p = blockIdx.x * 256 + tid;

  float xv[CIN];
#pragma unroll
  for (int i = 0; i < CIN; ++i) xv[i] = x[i * HW + p];

  float s = 0.f, s2 = 0.f;
  for (int o = 0; o < CH; ++o) {
    float a0 = 0.f, a1 = 0.f, a2 = 0.f, a3 = 0.f;
#pragma unroll
    for (int i = 0; i < CIN; i += 4) {
      a0 += swt[o * CIN + i]     * xv[i];
      a1 += swt[o * CIN + i + 1] * xv[i + 1];
      a2 += swt[o * CIN + i + 2] * xv[i + 2];
      a3 += swt[o * CIN + i + 3] * xv[i + 3];
    }
    float acc = (a0 + a1) + (a2 + a3);
    s += acc; s2 += acc * acc;
  }
  float mean = s * (1.f / CH);
  float var = s2 * (1.f / CH) - mean * mean;
  float rinv = rsqrtf(var + EPSV);
  for (int o = 0; o < CH; ++o) {
    float a0 = 0.f, a1 = 0.f, a2 = 0.f, a3 = 0.f;
#pragma unroll
    for (int i = 0; i < CIN; i += 4) {
      a0 += swt[o * CIN + i]     * xv[i];
      a1 += swt[o * CIN + i + 1] * xv[i + 1];
      a2 += swt[o * CIN + i + 2] * xv[i + 2];
      a3 += swt[o * CIN + i + 3] * xv[i + 3];
    }
    float acc = (a0 + a1) + (a2 + a3);
    feat[o * HW + p] = (acc - mean) * rinv * sg[o] + sb[o];
  }
}

// ---------------------------------------------------------------------------
// Kernel 2: r = relu(conv3x3(feat, df1_w)) -> rT bf16 [p][m] (transposed for MFMA B)
// ---------------------------------------------------------------------------
__global__ __launch_bounds__(256) void k_conv3(const float* __restrict__ feat_rgb,
                                               const float* __restrict__ feat_ev,
                                               const float* __restrict__ w3,  // [128][128][3][3]
                                               short* __restrict__ rT_rgb,
                                               short* __restrict__ rT_ev) {
  __shared__ __align__(16) float wl[CH * 9 * 8];  // 36 KB
  int tid = threadIdx.x;
  int mb = blockIdx.y;  // 0..15, 8 m each
  for (int i = tid; i < CH * 9 * 8; i += 256) {
    int mi = i & 7;
    int tap = (i >> 3) % 9;
    int c = i / 72;
    wl[i] = w3[((mb * 8 + mi) * CH + c) * 9 + tap];
  }
  __syncthreads();
  const float* feat = blockIdx.z ? feat_ev : feat_rgb;
  short* rT = blockIdx.z ? rT_ev : rT_rgb;
  int strip = blockIdx.x;  // 2 rows per strip
  int ty = tid >> 7;
  int tx = tid & 127;
  int h = strip * 2 + ty;
  float acc[8];
#pragma unroll
  for (int mi = 0; mi < 8; ++mi) acc[mi] = 0.f;
  bool up_ok = h > 0, dn_ok = h < HD - 1;
  bool lf_ok = tx > 0, rt_ok = tx < WD - 1;
  for (int c = 0; c < CH; ++c) {
    const float* fb = feat + c * HW + h * WD + tx;
    float f[9];
    f[0] = (up_ok && lf_ok) ? fb[-WD - 1] : 0.f;
    f[1] = up_ok ? fb[-WD] : 0.f;
    f[2] = (up_ok && rt_ok) ? fb[-WD + 1] : 0.f;
    f[3] = lf_ok ? fb[-1] : 0.f;
    f[4] = fb[0];
    f[5] = rt_ok ? fb[1] : 0.f;
    f[6] = (dn_ok && lf_ok) ? fb[WD - 1] : 0.f;
    f[7] = dn_ok ? fb[WD] : 0.f;
    f[8] = (dn_ok && rt_ok) ? fb[WD + 1] : 0.f;
#pragma unroll
    for (int tap = 0; tap < 9; ++tap) {
      const float4* wp = (const float4*)&wl[(c * 9 + tap) * 8];
      float4 w0 = wp[0], w1 = wp[1];
      acc[0] += w0.x * f[tap]; acc[1] += w0.y * f[tap];
      acc[2] += w0.z * f[tap]; acc[3] += w0.w * f[tap];
      acc[4] += w1.x * f[tap]; acc[5] += w1.y * f[tap];
      acc[6] += w1.z * f[tap]; acc[7] += w1.w * f[tap];
    }
  }
  int p = h * WD + tx;
  short8 v;
#pragma unroll
  for (int mi = 0; mi < 8; ++mi) v[mi] = f2bf(fmaxf(acc[mi], 0.f));
  ((short8*)rT)[p * 16 + mb] = v;
}

// ---------------------------------------------------------------------------
// Prep: df2 [3200][128] fp32 -> df2p [128 c][32 taps (25 used)][128 k] bf16
// ---------------------------------------------------------------------------
__global__ __launch_bounds__(256) void k_prep_df2(const float* __restrict__ df2,
                                                  short* __restrict__ df2p) {
  int idx = blockIdx.x * 256 + threadIdx.x;  // 524288 total
  int c = idx >> 12, t = (idx >> 7) & 31, k = idx & 127;
  float v = (t < 25) ? df2[(c * 25 + t) * CH + k] : 0.f;
  df2p[idx] = f2bf(v);
}

// ---------------------------------------------------------------------------
// Kernel 3 (dominant): MFMA fused dynamic-filter gen + 5x5 apply.
//   S[c][tap][px] = df2p[c] (32x128 bf16) @ rT (128 x 16px bf16)  via mfma 16x16x32
//   en[c][px] = sum_tap featwin(c,tap,px) * S   (tap reduce via shfl_xor 16/32)
// Block: 4 waves, 16x16 px tile, c-chunk of 32 (grid.y=4). No LDS.
// ---------------------------------------------------------------------------
__global__ __launch_bounds__(256) void k_filt_mfma(
    const float* __restrict__ feat_rgb, const float* __restrict__ feat_ev,
    const short* __restrict__ rT_rgb, const short* __restrict__ rT_ev,
    const short* __restrict__ df2p,
    float* __restrict__ en_rgb, float* __restrict__ en_ev) {
  const float* feat = blockIdx.z ? feat_ev : feat_rgb;
  const short* rT = blockIdx.z ? rT_ev : rT_rgb;
  float* en = blockIdx.z ? en_ev : en_rgb;
  int tid = threadIdx.x;
  int wave = tid >> 6, lane = tid & 63;
  int col = lane & 15, grp = lane >> 4;
  int ty0 = (blockIdx.x >> 3) * 16, tx0 = (blockIdx.x & 7) * 16;
  int c0 = blockIdx.y * 32;
  int py0 = ty0 + wave * 4;
  int pxx = tx0 + col;

  // B fragments: wave's 4 row-subtiles x 4 k-chunks, resident for whole c-loop
  short8 rv[4][4];
#pragma unroll
  for (int s = 0; s < 4; ++s) {
    const short8* bp = (const short8*)(rT + ((py0 + s) * WD + pxx) * CH);
#pragma unroll
    for (int q = 0; q < 4; ++q) rv[s][q] = bp[q * 4 + grp];
  }

  // epilogue feat offsets (clamped) + validity mask, per subtile x 8 tap-slots
  unsigned off[4][8];
  unsigned vmask = 0;
#pragma unroll
  for (int s = 0; s < 4; ++s) {
#pragma unroll
    for (int j = 0; j < 8; ++j) {
      int tap = (j < 4) ? (grp * 4 + j) : (16 + grp * 4 + (j - 4));
      int dy = tap / 5 - 2, dx = tap % 5 - 2;
      int yy = py0 + s + dy, xx = pxx + dx;
      bool v = (tap < 25) && yy >= 0 && yy < HD && xx >= 0 && xx < WD;
      int yyc = min(max(yy, 0), HD - 1), xxc = min(max(xx, 0), WD - 1);
      off[s][j] = (unsigned)(yyc * WD + xxc);
      if (v) vmask |= 1u << (s * 8 + j);
    }
  }

  for (int c = c0; c < c0 + 32; ++c) {
    const short8* ap = (const short8*)(df2p) + (size_t)c * 512;
    short8 a0[4], a1[4];
#pragma unroll
    for (int q = 0; q < 4; ++q) {
      a0[q] = ap[col * 16 + q * 4 + grp];
      a1[q] = ap[(16 + col) * 16 + q * 4 + grp];
    }
    const float* fc = feat + c * HW;
    float* ec = en + c * HW;
#pragma unroll
    for (int s = 0; s < 4; ++s) {
      f32x4 acc0 = {0.f, 0.f, 0.f, 0.f}, acc1 = {0.f, 0.f, 0.f, 0.f};
#pragma unroll
      for (int q = 0; q < 4; ++q) {
        acc0 = __builtin_amdgcn_mfma_f32_16x16x32_bf16(a0[q], rv[s][q], acc0, 0, 0, 0);
        acc1 = __builtin_amdgcn_mfma_f32_16x16x32_bf16(a1[q], rv[s][q], acc1, 0, 0, 0);
      }
      float partial = 0.f;
#pragma unroll
      for (int r = 0; r < 4; ++r) {
        float f0 = ((vmask >> (s * 8 + r)) & 1u) ? fc[off[s][r]] : 0.f;
        float f1 = ((vmask >> (s * 8 + 4 + r)) & 1u) ? fc[off[s][4 + r]] : 0.f;
        partial += f0 * acc0[r] + f1 * acc1[r];
      }
      partial += __shfl_xor(partial, 16);
      partial += __shfl_xor(partial, 32);
      if (lane < 16) ec[(py0 + s) * WD + pxx] = partial;
    }
  }
}

// ---------------------------------------------------------------------------
// Kernel 4: fused = en_rgb * (1 + sigmoid(sp_w @ en_ev)) + feat_rgb
// ---------------------------------------------------------------------------
__global__ __launch_bounds__(256) void k_fuse(
    const float* __restrict__ en_rgb, const float* __restrict__ en_ev,
    const float* __restrict__ feat_rgb, const float* __restrict__ sp_w,
    float* __restrict__ fused) {
  __shared__ __align__(16) float sw[CH * CH];  // 64 KB
  int tid = threadIdx.x;
  for (int i = tid; i < CH * CH; i += 256) sw[i] = sp_w[i];
  __syncthreads();
  int p = blockIdx.x * 256 + tid;
  float evv[CH];
#pragma unroll
  for (int i = 0; i < CH; ++i) evv[i] = en_ev[i * HW + p];
  for (int o = 0; o < CH; ++o) {
    float a0 = 0.f, a1 = 0.f, a2 = 0.f, a3 = 0.f;
#pragma unroll
    for (int i = 0; i < CH; i += 4) {
      a0 += sw[o * CH + i]     * evv[i];
      a1 += sw[o * CH + i + 1] * evv[i + 1];
      a2 += sw[o * CH + i + 2] * evv[i + 2];
      a3 += sw[o * CH + i + 3] * evv[i + 3];
    }
    float z = (a0 + a1) + (a2 + a3);
    float sg = 1.f / (1.f + __expf(-z));
    fused[o * HW + p] = en_rgb[o * HW + p] * (1.f + sg) + feat_rgb[o * HW + p];
  }
}

// ---------------------------------------------------------------------------
// Kernel 5: out = out_w @ LayerNorm_c(fused)
// ---------------------------------------------------------------------------
__global__ __launch_bounds__(256) void k_out(
    const float* __restrict__ fused, const float* __restrict__ g,
    const float* __restrict__ b, const float* __restrict__ out_w,
    float* __restrict__ out) {
  __shared__ __align__(16) float sw[64 * CH];  // 32 KB
  __shared__ float sg[CH], sb[CH];
  int tid = threadIdx.x;
  for (int i = tid; i < 64 * CH; i += 256) sw[i] = out_w[i];
  if (tid < CH) { sg[tid] = g[tid]; sb[tid] = b[tid]; }
  __syncthreads();
  int p = blockIdx.x * 256 + tid;
  float v[CH];
  float s = 0.f, s2 = 0.f;
#pragma unroll
  for (int i = 0; i < CH; ++i) {
    v[i] = fused[i * HW + p];
    s += v[i]; s2 += v[i] * v[i];
  }
  float mean = s * (1.f / CH), var = s2 * (1.f / CH) - mean * mean;
  float rinv = rsqrtf(var + EPSV);
#pragma unroll
  for (int i = 0; i < CH; ++i) v[i] = (v[i] - mean) * rinv * sg[i] + sb[i];
  for (int q = 0; q < 64; ++q) {
    float a0 = 0.f, a1 = 0.f, a2 = 0.f, a3 = 0.f;
#pragma unroll
    for (int i = 0; i < CH; i += 4) {
      a0 += sw[q * CH + i]     * v[i];
      a1 += sw[q * CH + i + 1] * v[i + 1];
      a2 += sw[q * CH + i + 2] * v[i + 2];
      a3 += sw[q * CH + i + 3] * v[i + 3];
    }
    out[q * HW + p] = (a0 + a1) + (a2 + a3);
  }
}

extern "C" void kernel_launch(void* const* d_in, const int* in_sizes, int n_in,
                              void* d_out, int out_size, void* d_ws, size_t ws_size,
                              hipStream_t stream) {
  const float* rgb  = (const float*)d_in[0];
  const float* ev   = (const float*)d_in[1];
  const float* cw   = (const float*)d_in[2];
  const float* g    = (const float*)d_in[3];
  const float* b    = (const float*)d_in[4];
  const float* w3   = (const float*)d_in[5];
  const float* df2  = (const float*)d_in[6];
  const float* spw  = (const float*)d_in[7];
  const float* outw = (const float*)d_in[8];
  float* out = (float*)d_out;
  char* wsb = (char*)d_ws;

  float* feat_rgb = (float*)(wsb);                    // 8 MB
  float* feat_ev  = (float*)(wsb + (8u << 20));       // 8 MB
  float* en_rgb   = (float*)(wsb + (16u << 20));      // 8 MB
  float* en_ev    = (float*)(wsb + (24u << 20));      // 8 MB
  short* rT_rgb   = (short*)(wsb + (32u << 20));      // 4 MB
  short* rT_ev    = (short*)(wsb + (36u << 20));      // 4 MB
  short* df2p     = (short*)(wsb + (40u << 20));      // 1 MB
  float* fused    = (float*)(wsb + (32u << 20));      // reuse rT (dead after k_filt)

  hipLaunchKernelGGL(k_prep_df2, dim3(2048), dim3(256), 0, stream, df2, df2p);
  hipLaunchKernelGGL(k_feat, dim3(64, 1, 2), dim3(256), 0, stream,
                     rgb, ev, cw, g, b, feat_rgb, feat_ev);
  hipLaunchKernelGGL(k_conv3, dim3(64, 16, 2), dim3(256), 0, stream,
                     feat_rgb, feat_ev, w3, rT_rgb, rT_ev);
  hipLaunchKernelGGL(k_filt_mfma, dim3(64, 4, 2), dim3(256), 0, stream,
                     feat_rgb, feat_ev, rT_rgb, rT_ev, df2p, en_rgb, en_ev);
  hipLaunchKernelGGL(k_fuse, dim3(64), dim3(256), 0, stream,
                     en_rgb, en_ev, feat_rgb, spw, fused);
  hipLaunchKernelGGL(k_out, dim3(64), dim3(256), 0, stream,
                     fused, g, b, outw, out);
}

// Round 3
// 319.482 us; speedup vs baseline: 5.9436x; 1.5653x over previous
//
#include <hip/hip_runtime.h>
#include <math.h>

#define HW 16384
#define WD 128
#define HD 128
#define CIN 64
#define CH 128
#define EPSV 1e-5f

typedef __attribute__((ext_vector_type(8))) short short8;
typedef __attribute__((ext_vector_type(4))) short short4v;
typedef __attribute__((ext_vector_type(4))) float f32x4;

__device__ __forceinline__ short f2bf(float x) {
  unsigned u = __float_as_uint(x);
  u += 0x7FFFu + ((u >> 16) & 1u);   // RNE
  return (short)(u >> 16);
}

// ---------------------------------------------------------------------------
// Prep: x [64][HW] fp32 -> xT [p][64] bf16   (coalesced reads, 16B stores)
// ---------------------------------------------------------------------------
__global__ __launch_bounds__(256) void k_prep_x(const float* __restrict__ rgb,
                                                const float* __restrict__ ev,
                                                short* __restrict__ xT_rgb,
                                                short* __restrict__ xT_ev) {
  const float* x = blockIdx.z ? ev : rgb;
  short* xT = blockIdx.z ? xT_ev : xT_rgb;
  int p = blockIdx.x * 256 + threadIdx.x;
#pragma unroll
  for (int cb = 0; cb < 8; ++cb) {
    short8 v;
#pragma unroll
    for (int j = 0; j < 8; ++j) v[j] = f2bf(x[(cb * 8 + j) * HW + p]);
    *(short8*)(xT + p * CIN + cb * 8) = v;
  }
}

// ---------------------------------------------------------------------------
// Prep: cw [128][64] fp32 -> A-frag layout [q2][m128][grp4][j8] bf16
// ---------------------------------------------------------------------------
__global__ __launch_bounds__(256) void k_prep_cw(const float* __restrict__ cw,
                                                 short* __restrict__ cwp) {
  int idx = blockIdx.x * 256 + threadIdx.x;  // 8192
  int j = idx & 7, grp = (idx >> 3) & 3, m = (idx >> 5) & 127, q = idx >> 12;
  cwp[idx] = f2bf(cw[m * CIN + q * 32 + grp * 8 + j]);
}

// ---------------------------------------------------------------------------
// Prep: w3 [128][128][3][3] fp32 -> A-frag layout [ks36][m128][grp4][j8] bf16
//   ks = tap*4 + q,  c = q*32 + grp*8 + j
// ---------------------------------------------------------------------------
__global__ __launch_bounds__(256) void k_prep_w3(const float* __restrict__ w3,
                                                 short* __restrict__ w3p) {
  int idx = blockIdx.x * 256 + threadIdx.x;  // 147456
  int j = idx & 7, grp = (idx >> 3) & 3, m = (idx >> 5) & 127, ks = idx >> 12;
  int tap = ks >> 2, q = ks & 3;
  int c = q * 32 + grp * 8 + j;
  w3p[idx] = f2bf(w3[(m * CH + c) * 9 + tap]);
}

// ---------------------------------------------------------------------------
// Prep: df2 [3200][128] fp32 -> df2p [128 c][32 taps (25 used)][128 k] bf16
// ---------------------------------------------------------------------------
__global__ __launch_bounds__(256) void k_prep_df2(const float* __restrict__ df2,
                                                  short* __restrict__ df2p) {
  int idx = blockIdx.x * 256 + threadIdx.x;  // 524288
  int c = idx >> 12, t = (idx >> 7) & 31, k = idx & 127;
  float v = (t < 25) ? df2[(c * 25 + t) * CH + k] : 0.f;
  df2p[idx] = f2bf(v);
}

// ---------------------------------------------------------------------------
// Kernel 1 (MFMA): feat = LN_c(conv1x1(x, cw)); writes feat fp32 + featT bf16.
// Wave = 16 px; K=64 -> 2 K-steps x 8 m-tiles. LN via shfl_xor(16/32) over grp.
// ---------------------------------------------------------------------------
__global__ __launch_bounds__(256) void k_feat_mfma(
    const short* __restrict__ xT_rgb, const short* __restrict__ xT_ev,
    const short* __restrict__ cwp, const float* __restrict__ g,
    const float* __restrict__ b,
    float* __restrict__ feat_rgb, float* __restrict__ feat_ev,
    short* __restrict__ featT_rgb, short* __restrict__ featT_ev) {
  __shared__ float sg[CH], sb[CH];
  int tid = threadIdx.x;
  if (tid < CH) { sg[tid] = g[tid]; sb[tid] = b[tid]; }
  __syncthreads();
  const short* xT = blockIdx.z ? xT_ev : xT_rgb;
  float* feat = blockIdx.z ? feat_ev : feat_rgb;
  short* featT = blockIdx.z ? featT_ev : featT_rgb;
  int wave = tid >> 6, lane = tid & 63, col = lane & 15, grp = lane >> 4;
  int p = blockIdx.x * 64 + wave * 16 + col;

  const short8* bp = (const short8*)(xT + p * CIN);
  short8 bq0 = bp[grp], bq1 = bp[4 + grp];
  const short8* ap = (const short8*)cwp;

  f32x4 acc[8];
#pragma unroll
  for (int mt = 0; mt < 8; ++mt) {
    acc[mt] = (f32x4){0.f, 0.f, 0.f, 0.f};
    short8 a0 = ap[(0 * 128 + mt * 16 + col) * 4 + grp];
    short8 a1 = ap[(1 * 128 + mt * 16 + col) * 4 + grp];
    acc[mt] = __builtin_amdgcn_mfma_f32_16x16x32_bf16(a0, bq0, acc[mt], 0, 0, 0);
    acc[mt] = __builtin_amdgcn_mfma_f32_16x16x32_bf16(a1, bq1, acc[mt], 0, 0, 0);
  }
  float s = 0.f, s2 = 0.f;
#pragma unroll
  for (int mt = 0; mt < 8; ++mt)
#pragma unroll
    for (int r = 0; r < 4; ++r) { float v = acc[mt][r]; s += v; s2 += v * v; }
  s += __shfl_xor(s, 16);  s += __shfl_xor(s, 32);
  s2 += __shfl_xor(s2, 16); s2 += __shfl_xor(s2, 32);
  float mean = s * (1.f / CH);
  float var = s2 * (1.f / CH) - mean * mean;
  float rinv = rsqrtf(var + EPSV);
#pragma unroll
  for (int mt = 0; mt < 8; ++mt) {
    short4v fv;
#pragma unroll
    for (int r = 0; r < 4; ++r) {
      int m = mt * 16 + grp * 4 + r;
      float v = (acc[mt][r] - mean) * rinv * sg[m] + sb[m];
      feat[m * HW + p] = v;
      fv[r] = f2bf(v);
    }
    *(short4v*)(featT + p * CH + mt * 16 + grp * 4) = fv;
  }
}

// ---------------------------------------------------------------------------
// Kernel 2 (MFMA): rT = bf16(relu(conv3x3(feat, df1_w))), implicit im2col.
// K = 9 taps x 128 c = 36 K-steps of 32 (tap-major).  Wave = 2 rows x 16 cols.
// Block = 4 waves = 8 rows x 16 cols; 256 blocks total.
// ---------------------------------------------------------------------------
__global__ __launch_bounds__(256) void k_conv3_mfma(
    const short* __restrict__ featT_rgb, const short* __restrict__ featT_ev,
    const short* __restrict__ w3p,
    short* __restrict__ rT_rgb, short* __restrict__ rT_ev) {
  const short* featT = blockIdx.z ? featT_ev : featT_rgb;
  short* rT = blockIdx.z ? rT_ev : rT_rgb;
  int tid = threadIdx.x, wave = tid >> 6, lane = tid & 63;
  int col = lane & 15, grp = lane >> 4;
  int ty = (blockIdx.x >> 3) * 8 + wave * 2;
  int tx = (blockIdx.x & 7) * 16;
  int x = tx + col;

  f32x4 acc[2][8];
#pragma unroll
  for (int s = 0; s < 2; ++s)
#pragma unroll
    for (int mt = 0; mt < 8; ++mt) acc[s][mt] = (f32x4){0.f, 0.f, 0.f, 0.f};

  const short8* ap = (const short8*)w3p;
  for (int ks = 0; ks < 36; ++ks) {
    int tap = ks >> 2, q = ks & 3;
    int dy = tap / 3 - 1, dx = tap % 3 - 1;
    int xs = x + dx;
    bool xok = (unsigned)xs < (unsigned)WD;
    int y0 = ty + dy, y1 = ty + 1 + dy;
    short8 b0 = {0, 0, 0, 0, 0, 0, 0, 0}, b1 = {0, 0, 0, 0, 0, 0, 0, 0};
    if (xok && (unsigned)y0 < (unsigned)HD)
      b0 = *(const short8*)(featT + (y0 * WD + xs) * CH + q * 32 + grp * 8);
    if (xok && (unsigned)y1 < (unsigned)HD)
      b1 = *(const short8*)(featT + (y1 * WD + xs) * CH + q * 32 + grp * 8);
#pragma unroll
    for (int mt = 0; mt < 8; ++mt) {
      short8 a = ap[(ks * 128 + mt * 16 + col) * 4 + grp];
      acc[0][mt] = __builtin_amdgcn_mfma_f32_16x16x32_bf16(a, b0, acc[0][mt], 0, 0, 0);
      acc[1][mt] = __builtin_amdgcn_mfma_f32_16x16x32_bf16(a, b1, acc[1][mt], 0, 0, 0);
    }
  }
#pragma unroll
  for (int s = 0; s < 2; ++s) {
    int p = (ty + s) * WD + x;
#pragma unroll
    for (int mt = 0; mt < 8; ++mt) {
      short4v v;
#pragma unroll
      for (int r = 0; r < 4; ++r) v[r] = f2bf(fmaxf(acc[s][mt][r], 0.f));
      *(short4v*)(rT + p * CH + mt * 16 + grp * 4) = v;
    }
  }
}

// ---------------------------------------------------------------------------
// Kernel 3: MFMA fused dynamic-filter gen + 5x5 apply (unchanged from R2).
// ---------------------------------------------------------------------------
__global__ __launch_bounds__(256) void k_filt_mfma(
    const float* __restrict__ feat_rgb, const float* __restrict__ feat_ev,
    const short* __restrict__ rT_rgb, const short* __restrict__ rT_ev,
    const short* __restrict__ df2p,
    float* __restrict__ en_rgb, float* __restrict__ en_ev) {
  const float* feat = blockIdx.z ? feat_ev : feat_rgb;
  const short* rT = blockIdx.z ? rT_ev : rT_rgb;
  float* en = blockIdx.z ? en_ev : en_rgb;
  int tid = threadIdx.x;
  int wave = tid >> 6, lane = tid & 63;
  int col = lane & 15, grp = lane >> 4;
  int ty0 = (blockIdx.x >> 3) * 16, tx0 = (blockIdx.x & 7) * 16;
  int c0 = blockIdx.y * 32;
  int py0 = ty0 + wave * 4;
  int pxx = tx0 + col;

  short8 rv[4][4];
#pragma unroll
  for (int s = 0; s < 4; ++s) {
    const short8* bp = (const short8*)(rT + ((py0 + s) * WD + pxx) * CH);
#pragma unroll
    for (int q = 0; q < 4; ++q) rv[s][q] = bp[q * 4 + grp];
  }

  unsigned off[4][8];
  unsigned vmask = 0;
#pragma unroll
  for (int s = 0; s < 4; ++s) {
#pragma unroll
    for (int j = 0; j < 8; ++j) {
      int tap = (j < 4) ? (grp * 4 + j) : (16 + grp * 4 + (j - 4));
      int dy = tap / 5 - 2, dx = tap % 5 - 2;
      int yy = py0 + s + dy, xx = pxx + dx;
      bool v = (tap < 25) && yy >= 0 && yy < HD && xx >= 0 && xx < WD;
      int yyc = min(max(yy, 0), HD - 1), xxc = min(max(xx, 0), WD - 1);
      off[s][j] = (unsigned)(yyc * WD + xxc);
      if (v) vmask |= 1u << (s * 8 + j);
    }
  }

  for (int c = c0; c < c0 + 32; ++c) {
    const short8* ap = (const short8*)(df2p) + (size_t)c * 512;
    short8 a0[4], a1[4];
#pragma unroll
    for (int q = 0; q < 4; ++q) {
      a0[q] = ap[col * 16 + q * 4 + grp];
      a1[q] = ap[(16 + col) * 16 + q * 4 + grp];
    }
    const float* fc = feat + c * HW;
    float* ec = en + c * HW;
#pragma unroll
    for (int s = 0; s < 4; ++s) {
      f32x4 acc0 = {0.f, 0.f, 0.f, 0.f}, acc1 = {0.f, 0.f, 0.f, 0.f};
#pragma unroll
      for (int q = 0; q < 4; ++q) {
        acc0 = __builtin_amdgcn_mfma_f32_16x16x32_bf16(a0[q], rv[s][q], acc0, 0, 0, 0);
        acc1 = __builtin_amdgcn_mfma_f32_16x16x32_bf16(a1[q], rv[s][q], acc1, 0, 0, 0);
      }
      float partial = 0.f;
#pragma unroll
      for (int r = 0; r < 4; ++r) {
        float f0 = ((vmask >> (s * 8 + r)) & 1u) ? fc[off[s][r]] : 0.f;
        float f1 = ((vmask >> (s * 8 + 4 + r)) & 1u) ? fc[off[s][4 + r]] : 0.f;
        partial += f0 * acc0[r] + f1 * acc1[r];
      }
      partial += __shfl_xor(partial, 16);
      partial += __shfl_xor(partial, 32);
      if (lane < 16) ec[(py0 + s) * WD + pxx] = partial;
    }
  }
}

// ---------------------------------------------------------------------------
// Kernel 4: fused = en_rgb * (1 + sigmoid(sp_w @ en_ev)) + feat_rgb
// ---------------------------------------------------------------------------
__global__ __launch_bounds__(256) void k_fuse(
    const float* __restrict__ en_rgb, const float* __restrict__ en_ev,
    const float* __restrict__ feat_rgb, const float* __restrict__ sp_w,
    float* __restrict__ fused) {
  __shared__ __align__(16) float sw[CH * CH];  // 64 KB
  int tid = threadIdx.x;
  for (int i = tid; i < CH * CH; i += 256) sw[i] = sp_w[i];
  __syncthreads();
  int p = blockIdx.x * 256 + tid;
  float evv[CH];
#pragma unroll
  for (int i = 0; i < CH; ++i) evv[i] = en_ev[i * HW + p];
  for (int o = 0; o < CH; ++o) {
    float a0 = 0.f, a1 = 0.f, a2 = 0.f, a3 = 0.f;
#pragma unroll
    for (int i = 0; i < CH; i += 4) {
      a0 += sw[o * CH + i]     * evv[i];
      a1 += sw[o * CH + i + 1] * evv[i + 1];
      a2 += sw[o * CH + i + 2] * evv[i + 2];
      a3 += sw[o * CH + i + 3] * evv[i + 3];
    }
    float z = (a0 + a1) + (a2 + a3);
    float sg = 1.f / (1.f + __expf(-z));
    fused[o * HW + p] = en_rgb[o * HW + p] * (1.f + sg) + feat_rgb[o * HW + p];
  }
}

// ---------------------------------------------------------------------------
// Kernel 5: out = out_w @ LayerNorm_c(fused)
// ---------------------------------------------------------------------------
__global__ __launch_bounds__(256) void k_out(
    const float* __restrict__ fused, const float* __restrict__ g,
    const float* __restrict__ b, const float* __restrict__ out_w,
    float* __restrict__ out) {
  __shared__ __align__(16) float sw[64 * CH];  // 32 KB
  __shared__ float sg[CH], sb[CH];
  int tid = threadIdx.x;
  for (int i = tid; i < 64 * CH; i += 256) sw[i] = out_w[i];
  if (tid < CH) { sg[tid] = g[tid]; sb[tid] = b[tid]; }
  __syncthreads();
  int p = blockIdx.x * 256 + tid;
  float v[CH];
  float s = 0.f, s2 = 0.f;
#pragma unroll
  for (int i = 0; i < CH; ++i) {
    v[i] = fused[i * HW + p];
    s += v[i]; s2 += v[i] * v[i];
  }
  float mean = s * (1.f / CH), var = s2 * (1.f / CH) - mean * mean;
  float rinv = rsqrtf(var + EPSV);
#pragma unroll
  for (int i = 0; i < CH; ++i) v[i] = (v[i] - mean) * rinv * sg[i] + sb[i];
  for (int q = 0; q < 64; ++q) {
    float a0 = 0.f, a1 = 0.f, a2 = 0.f, a3 = 0.f;
#pragma unroll
    for (int i = 0; i < CH; i += 4) {
      a0 += sw[q * CH + i]     * v[i];
      a1 += sw[q * CH + i + 1] * v[i + 1];
      a2 += sw[q * CH + i + 2] * v[i + 2];
      a3 += sw[q * CH + i + 3] * v[i + 3];
    }
    out[q * HW + p] = (a0 + a1) + (a2 + a3);
  }
}

extern "C" void kernel_launch(void* const* d_in, const int* in_sizes, int n_in,
                              void* d_out, int out_size, void* d_ws, size_t ws_size,
                              hipStream_t stream) {
  const float* rgb  = (const float*)d_in[0];
  const float* ev   = (const float*)d_in[1];
  const float* cw   = (const float*)d_in[2];
  const float* g    = (const float*)d_in[3];
  const float* b    = (const float*)d_in[4];
  const float* w3   = (const float*)d_in[5];
  const float* df2  = (const float*)d_in[6];
  const float* spw  = (const float*)d_in[7];
  const float* outw = (const float*)d_in[8];
  float* out = (float*)d_out;
  char* wsb = (char*)d_ws;

  const size_t MB = 1u << 20;
  float* feat_rgb  = (float*)(wsb);             // 8 MB
  float* feat_ev   = (float*)(wsb + 8 * MB);    // 8 MB
  float* en_rgb    = (float*)(wsb + 16 * MB);   // 8 MB
  float* en_ev     = (float*)(wsb + 24 * MB);   // 8 MB
  short* rT_rgb    = (short*)(wsb + 32 * MB);   // 4 MB
  short* rT_ev     = (short*)(wsb + 36 * MB);   // 4 MB
  short* featT_rgb = (short*)(wsb + 40 * MB);   // 4 MB
  short* featT_ev  = (short*)(wsb + 44 * MB);   // 4 MB
  short* xT_rgb    = (short*)(wsb + 48 * MB);   // 2 MB
  short* xT_ev     = (short*)(wsb + 50 * MB);   // 2 MB
  short* df2p      = (short*)(wsb + 52 * MB);   // 1 MB
  short* w3p       = (short*)(wsb + 53 * MB);   // 288 KB
  short* cwp       = (short*)(wsb + 54 * MB);   // 16 KB
  float* fused     = (float*)(wsb + 32 * MB);   // reuse rT_* (dead after k_filt)

  hipLaunchKernelGGL(k_prep_x, dim3(64, 1, 2), dim3(256), 0, stream,
                     rgb, ev, xT_rgb, xT_ev);
  hipLaunchKernelGGL(k_prep_cw, dim3(32), dim3(256), 0, stream, cw, cwp);
  hipLaunchKernelGGL(k_prep_w3, dim3(576), dim3(256), 0, stream, w3, w3p);
  hipLaunchKernelGGL(k_prep_df2, dim3(2048), dim3(256), 0, stream, df2, df2p);
  hipLaunchKernelGGL(k_feat_mfma, dim3(256, 1, 2), dim3(256), 0, stream,
                     xT_rgb, xT_ev, cwp, g, b, feat_rgb, feat_ev, featT_rgb, featT_ev);
  hipLaunchKernelGGL(k_conv3_mfma, dim3(128, 1, 2), dim3(256), 0, stream,
                     featT_rgb, featT_ev, w3p, rT_rgb, rT_ev);
  hipLaunchKernelGGL(k_filt_mfma, dim3(64, 4, 2), dim3(256), 0, stream,
                     feat_rgb, feat_ev, rT_rgb, rT_ev, df2p, en_rgb, en_ev);
  hipLaunchKernelGGL(k_fuse, dim3(64), dim3(256), 0, stream,
                     en_rgb, en_ev, feat_rgb, spw, fused);
  hipLaunchKernelGGL(k_out, dim3(64), dim3(256), 0, stream,
                     fused, g, b, outw, out);
}

// Round 4
// 160.963 us; speedup vs baseline: 11.7968x; 1.9848x over previous
//
#include <hip/hip_runtime.h>
#include <math.h>

#define HW 16384
#define WD 128
#define HD 128
#define CIN 64
#define CH 128
#define EPSV 1e-5f

typedef __attribute__((ext_vector_type(8))) short short8;
typedef __attribute__((ext_vector_type(4))) short short4v;
typedef __attribute__((ext_vector_type(4))) float f32x4;

__device__ __forceinline__ short f2bf(float x) {
  unsigned u = __float_as_uint(x);
  u += 0x7FFFu + ((u >> 16) & 1u);   // RNE
  return (short)(u >> 16);
}
__device__ __forceinline__ float bf2f(short x) {
  return __uint_as_float(((unsigned)(unsigned short)x) << 16);
}

// ---------------------------------------------------------------------------
// Prep: x [64][HW] fp32 -> xT [p][64] bf16
// ---------------------------------------------------------------------------
__global__ __launch_bounds__(256) void k_prep_x(const float* __restrict__ rgb,
                                                const float* __restrict__ ev,
                                                short* __restrict__ xT_rgb,
                                                short* __restrict__ xT_ev) {
  const float* x = blockIdx.z ? ev : rgb;
  short* xT = blockIdx.z ? xT_ev : xT_rgb;
  int p = blockIdx.x * 256 + threadIdx.x;
#pragma unroll
  for (int cb = 0; cb < 8; ++cb) {
    short8 v;
#pragma unroll
    for (int j = 0; j < 8; ++j) v[j] = f2bf(x[(cb * 8 + j) * HW + p]);
    *(short8*)(xT + p * CIN + cb * 8) = v;
  }
}

// ---------------------------------------------------------------------------
// Weight preps -> A-frag layout [q][m][grp4][j8] bf16
// ---------------------------------------------------------------------------
__global__ __launch_bounds__(256) void k_prep_cw(const float* __restrict__ cw,
                                                 short* __restrict__ cwp) {
  int idx = blockIdx.x * 256 + threadIdx.x;  // 8192: q2 x m128
  int j = idx & 7, grp = (idx >> 3) & 3, m = (idx >> 5) & 127, q = idx >> 12;
  cwp[idx] = f2bf(cw[m * CIN + q * 32 + grp * 8 + j]);
}

__global__ __launch_bounds__(256) void k_prep_w3(const float* __restrict__ w3,
                                                 short* __restrict__ w3p) {
  int idx = blockIdx.x * 256 + threadIdx.x;  // 147456: ks36 x m128
  int j = idx & 7, grp = (idx >> 3) & 3, m = (idx >> 5) & 127, ks = idx >> 12;
  int tap = ks >> 2, q = ks & 3;
  int c = q * 32 + grp * 8 + j;
  w3p[idx] = f2bf(w3[(m * CH + c) * 9 + tap]);
}

__global__ __launch_bounds__(256) void k_prep_df2(const float* __restrict__ df2,
                                                  short* __restrict__ df2p) {
  int idx = blockIdx.x * 256 + threadIdx.x;  // 524288: [c128][t32][k128]
  int c = idx >> 12, t = (idx >> 7) & 31, k = idx & 127;
  float v = (t < 25) ? df2[(c * 25 + t) * CH + k] : 0.f;
  df2p[idx] = f2bf(v);
}

__global__ __launch_bounds__(256) void k_prep_spw(const float* __restrict__ spw,
                                                  short* __restrict__ spwp) {
  int idx = blockIdx.x * 256 + threadIdx.x;  // 16384: q4 x m128
  int j = idx & 7, grp = (idx >> 3) & 3, m = (idx >> 5) & 127, q = idx >> 12;
  spwp[idx] = f2bf(spw[m * CH + q * 32 + grp * 8 + j]);
}

__global__ __launch_bounds__(256) void k_prep_outw(const float* __restrict__ outw,
                                                   short* __restrict__ outwp) {
  int idx = blockIdx.x * 256 + threadIdx.x;  // 8192: q4 x m64
  int j = idx & 7, grp = (idx >> 3) & 3, m = (idx >> 5) & 63, q = idx >> 11;
  outwp[idx] = f2bf(outw[m * CH + q * 32 + grp * 8 + j]);
}

// ---------------------------------------------------------------------------
// Kernel 1 (MFMA): featT = bf16(LN_c(conv1x1(x, cw)))  [p][128]
// ---------------------------------------------------------------------------
__global__ __launch_bounds__(256) void k_feat_mfma(
    const short* __restrict__ xT_rgb, const short* __restrict__ xT_ev,
    const short* __restrict__ cwp, const float* __restrict__ g,
    const float* __restrict__ b,
    short* __restrict__ featT_rgb, short* __restrict__ featT_ev) {
  __shared__ float sg[CH], sb[CH];
  int tid = threadIdx.x;
  if (tid < CH) { sg[tid] = g[tid]; sb[tid] = b[tid]; }
  __syncthreads();
  const short* xT = blockIdx.z ? xT_ev : xT_rgb;
  short* featT = blockIdx.z ? featT_ev : featT_rgb;
  int wave = tid >> 6, lane = tid & 63, col = lane & 15, grp = lane >> 4;
  int p = blockIdx.x * 64 + wave * 16 + col;

  const short8* bp = (const short8*)(xT + p * CIN);
  short8 bq0 = bp[grp], bq1 = bp[4 + grp];
  const short8* ap = (const short8*)cwp;

  f32x4 acc[8];
#pragma unroll
  for (int mt = 0; mt < 8; ++mt) {
    acc[mt] = (f32x4){0.f, 0.f, 0.f, 0.f};
    short8 a0 = ap[(0 * 128 + mt * 16 + col) * 4 + grp];
    short8 a1 = ap[(1 * 128 + mt * 16 + col) * 4 + grp];
    acc[mt] = __builtin_amdgcn_mfma_f32_16x16x32_bf16(a0, bq0, acc[mt], 0, 0, 0);
    acc[mt] = __builtin_amdgcn_mfma_f32_16x16x32_bf16(a1, bq1, acc[mt], 0, 0, 0);
  }
  float s = 0.f, s2 = 0.f;
#pragma unroll
  for (int mt = 0; mt < 8; ++mt)
#pragma unroll
    for (int r = 0; r < 4; ++r) { float v = acc[mt][r]; s += v; s2 += v * v; }
  s += __shfl_xor(s, 16);  s += __shfl_xor(s, 32);
  s2 += __shfl_xor(s2, 16); s2 += __shfl_xor(s2, 32);
  float mean = s * (1.f / CH);
  float var = s2 * (1.f / CH) - mean * mean;
  float rinv = rsqrtf(var + EPSV);
#pragma unroll
  for (int mt = 0; mt < 8; ++mt) {
    short4v fv;
#pragma unroll
    for (int r = 0; r < 4; ++r) {
      int m = mt * 16 + grp * 4 + r;
      fv[r] = f2bf((acc[mt][r] - mean) * rinv * sg[m] + sb[m]);
    }
    *(short4v*)(featT + p * CH + mt * 16 + grp * 4) = fv;
  }
}

// ---------------------------------------------------------------------------
// Kernel 2 (MFMA): rT = bf16(relu(conv3x3(featT, df1_w))), implicit im2col.
// ---------------------------------------------------------------------------
__global__ __launch_bounds__(256) void k_conv3_mfma(
    const short* __restrict__ featT_rgb, const short* __restrict__ featT_ev,
    const short* __restrict__ w3p,
    short* __restrict__ rT_rgb, short* __restrict__ rT_ev) {
  const short* featT = blockIdx.z ? featT_ev : featT_rgb;
  short* rT = blockIdx.z ? rT_ev : rT_rgb;
  int tid = threadIdx.x, wave = tid >> 6, lane = tid & 63;
  int col = lane & 15, grp = lane >> 4;
  int ty = (blockIdx.x >> 3) * 8 + wave * 2;
  int tx = (blockIdx.x & 7) * 16;
  int x = tx + col;

  f32x4 acc[2][8];
#pragma unroll
  for (int s = 0; s < 2; ++s)
#pragma unroll
    for (int mt = 0; mt < 8; ++mt) acc[s][mt] = (f32x4){0.f, 0.f, 0.f, 0.f};

  const short8* ap = (const short8*)w3p;
  for (int ks = 0; ks < 36; ++ks) {
    int tap = ks >> 2, q = ks & 3;
    int dy = tap / 3 - 1, dx = tap % 3 - 1;
    int xs = x + dx;
    bool xok = (unsigned)xs < (unsigned)WD;
    int y0 = ty + dy, y1 = ty + 1 + dy;
    short8 b0 = {0, 0, 0, 0, 0, 0, 0, 0}, b1 = {0, 0, 0, 0, 0, 0, 0, 0};
    if (xok && (unsigned)y0 < (unsigned)HD)
      b0 = *(const short8*)(featT + (y0 * WD + xs) * CH + q * 32 + grp * 8);
    if (xok && (unsigned)y1 < (unsigned)HD)
      b1 = *(const short8*)(featT + (y1 * WD + xs) * CH + q * 32 + grp * 8);
#pragma unroll
    for (int mt = 0; mt < 8; ++mt) {
      short8 a = ap[(ks * 128 + mt * 16 + col) * 4 + grp];
      acc[0][mt] = __builtin_amdgcn_mfma_f32_16x16x32_bf16(a, b0, acc[0][mt], 0, 0, 0);
      acc[1][mt] = __builtin_amdgcn_mfma_f32_16x16x32_bf16(a, b1, acc[1][mt], 0, 0, 0);
    }
  }
#pragma unroll
  for (int s = 0; s < 2; ++s) {
    int p = (ty + s) * WD + x;
#pragma unroll
    for (int mt = 0; mt < 8; ++mt) {
      short4v v;
#pragma unroll
      for (int r = 0; r < 4; ++r) v[r] = f2bf(fmaxf(acc[s][mt][r], 0.f));
      *(short4v*)(rT + p * CH + mt * 16 + grp * 4) = v;
    }
  }
}

// ---------------------------------------------------------------------------
// Kernel 3: fused dynamic-filter gen + 5x5 apply, v2.
// c-chunk 16 (grid.y=8 -> 1024 blocks, 4 blocks/CU).  feat window staged in
// LDS as fp32 [16c][20][20] zero-padded; epilogue reads LDS (no vmask: padded
// df2 tap-rows >=25 give exact-zero MFMA output).  Writes enT bf16 [p][c].
// ---------------------------------------------------------------------------
__global__ __launch_bounds__(256) void k_filt_v2(
    const short* __restrict__ featT_rgb, const short* __restrict__ featT_ev,
    const short* __restrict__ rT_rgb, const short* __restrict__ rT_ev,
    const short* __restrict__ df2p,
    short* __restrict__ enT_rgb, short* __restrict__ enT_ev) {
  __shared__ float fw[16 * 400];   // 25.6 KB
  const short* featT = blockIdx.z ? featT_ev : featT_rgb;
  const short* rT = blockIdx.z ? rT_ev : rT_rgb;
  short* enT = blockIdx.z ? enT_ev : enT_rgb;
  int tid = threadIdx.x;
  int wave = tid >> 6, lane = tid & 63;
  int col = lane & 15, grp = lane >> 4;
  int ty0 = (blockIdx.x >> 3) * 16, tx0 = (blockIdx.x & 7) * 16;
  int c0 = blockIdx.y * 16;
  int py0 = ty0 + wave * 4;
  int pxx = tx0 + col;

  // stage zero-padded window rows ty0-2..ty0+17, cols tx0-2..tx0+17
  for (int px = tid; px < 400; px += 256) {
    int wr = px / 20, wc = px % 20;
    int y = ty0 + wr - 2, x = tx0 + wc - 2;
    float vals[16];
    if ((unsigned)y < (unsigned)HD && (unsigned)x < (unsigned)WD) {
      const short8* fp = (const short8*)(featT + (y * WD + x) * CH + c0);
      short8 v0 = fp[0], v1 = fp[1];
#pragma unroll
      for (int j = 0; j < 8; ++j) { vals[j] = bf2f(v0[j]); vals[8 + j] = bf2f(v1[j]); }
    } else {
#pragma unroll
      for (int j = 0; j < 16; ++j) vals[j] = 0.f;
    }
#pragma unroll
    for (int ci = 0; ci < 16; ++ci) fw[ci * 400 + px] = vals[ci];
  }

  // B fragments (independent of LDS -> overlap with staging)
  short8 rv[4][4];
#pragma unroll
  for (int s = 0; s < 4; ++s) {
    const short8* bp = (const short8*)(rT + ((py0 + s) * WD + pxx) * CH);
#pragma unroll
    for (int q = 0; q < 4; ++q) rv[s][q] = bp[q * 4 + grp];
  }

  // epilogue LDS indices (add s*20 per subtile at use)
  int idx0[4], idx1[4];
#pragma unroll
  for (int r = 0; r < 4; ++r) {
    int tap0 = grp * 4 + r;
    int tap1 = 16 + grp * 4 + r;
    idx0[r] = (wave * 4 + tap0 / 5) * 20 + col + tap0 % 5;
    idx1[r] = (wave * 4 + tap1 / 5) * 20 + col + tap1 % 5;
  }
  __syncthreads();

  for (int c = 0; c < 16; ++c) {
    const short8* ap = (const short8*)(df2p) + (size_t)(c0 + c) * 512;
    short8 a0[4], a1[4];
#pragma unroll
    for (int q = 0; q < 4; ++q) {
      a0[q] = ap[col * 16 + q * 4 + grp];
      a1[q] = ap[(16 + col) * 16 + q * 4 + grp];
    }
    const float* fwc = fw + c * 400;
#pragma unroll
    for (int s = 0; s < 4; ++s) {
      f32x4 acc0 = {0.f, 0.f, 0.f, 0.f}, acc1 = {0.f, 0.f, 0.f, 0.f};
#pragma unroll
      for (int q = 0; q < 4; ++q) {
        acc0 = __builtin_amdgcn_mfma_f32_16x16x32_bf16(a0[q], rv[s][q], acc0, 0, 0, 0);
        acc1 = __builtin_amdgcn_mfma_f32_16x16x32_bf16(a1[q], rv[s][q], acc1, 0, 0, 0);
      }
      float partial = 0.f;
#pragma unroll
      for (int r = 0; r < 4; ++r) {
        partial += fwc[idx0[r] + s * 20] * acc0[r];
        partial += fwc[idx1[r] + s * 20] * acc1[r];
      }
      partial += __shfl_xor(partial, 16);
      partial += __shfl_xor(partial, 32);
      if (lane < 16) enT[((py0 + s) * WD + pxx) * CH + c0 + c] = f2bf(partial);
    }
  }
}

// ---------------------------------------------------------------------------
// Kernel 4 (fused k_fuse + LN + k_out, all MFMA):
//   z = sp_w @ en_ev ; fused = en_rgb*(1+sigmoid(z)) + feat_rgb
//   out = out_w @ LN_c(fused)
// Wave = 16 px.  Norm values bounced through per-wave LDS (stride 136 shorts).
// ---------------------------------------------------------------------------
__global__ __launch_bounds__(256) void k_post(
    const short* __restrict__ enT_rgb, const short* __restrict__ enT_ev,
    const short* __restrict__ featT_rgb,
    const short* __restrict__ spwp, const short* __restrict__ outwp,
    const float* __restrict__ g, const float* __restrict__ b,
    float* __restrict__ out) {
  __shared__ short nlds[4][16 * 136];   // 17.4 KB
  __shared__ float sg[CH], sb[CH];
  int tid = threadIdx.x;
  if (tid < CH) { sg[tid] = g[tid]; sb[tid] = b[tid]; }
  __syncthreads();
  int wave = tid >> 6, lane = tid & 63, col = lane & 15, grp = lane >> 4;
  int p = blockIdx.x * 64 + wave * 16 + col;

  // gate GEMM: z[128 o][16 px] = sp_w @ en_ev
  const short8* bp = (const short8*)(enT_ev + p * CH);
  short8 bq[4];
#pragma unroll
  for (int q = 0; q < 4; ++q) bq[q] = bp[q * 4 + grp];
  const short8* ap = (const short8*)spwp;
  f32x4 z[8];
#pragma unroll
  for (int mt = 0; mt < 8; ++mt) {
    z[mt] = (f32x4){0.f, 0.f, 0.f, 0.f};
#pragma unroll
    for (int q = 0; q < 4; ++q)
      z[mt] = __builtin_amdgcn_mfma_f32_16x16x32_bf16(
          ap[(q * 128 + mt * 16 + col) * 4 + grp], bq[q], z[mt], 0, 0, 0);
  }

  // fused + LN stats
  const short4v* er = (const short4v*)(enT_rgb + p * CH);
  const short4v* fr = (const short4v*)(featT_rgb + p * CH);
  float fused[8][4];
  float s = 0.f, s2 = 0.f;
#pragma unroll
  for (int mt = 0; mt < 8; ++mt) {
    short4v e4 = er[mt * 4 + grp];
    short4v f4 = fr[mt * 4 + grp];
#pragma unroll
    for (int r = 0; r < 4; ++r) {
      float sig = 1.f / (1.f + __expf(-z[mt][r]));
      float f = bf2f(e4[r]) * (1.f + sig) + bf2f(f4[r]);
      fused[mt][r] = f; s += f; s2 += f * f;
    }
  }
  s += __shfl_xor(s, 16);  s += __shfl_xor(s, 32);
  s2 += __shfl_xor(s2, 16); s2 += __shfl_xor(s2, 32);
  float mean = s * (1.f / CH);
  float var = s2 * (1.f / CH) - mean * mean;
  float rinv = rsqrtf(var + EPSV);

  // normalize -> bf16 -> LDS [px][o] (stride 136)
  short* nl = &nlds[wave][0];
#pragma unroll
  for (int mt = 0; mt < 8; ++mt) {
    short4v nv;
#pragma unroll
    for (int r = 0; r < 4; ++r) {
      int o = mt * 16 + grp * 4 + r;
      nv[r] = f2bf((fused[mt][r] - mean) * rinv * sg[o] + sb[o]);
    }
    *(short4v*)(nl + col * 136 + mt * 16 + grp * 4) = nv;
  }

  // out GEMM: out[64 o][16 px] = out_w @ norm
  short8 nb[4];
#pragma unroll
  for (int q = 0; q < 4; ++q)
    nb[q] = *(const short8*)(nl + col * 136 + q * 32 + grp * 8);
  const short8* op = (const short8*)outwp;
#pragma unroll
  for (int mt = 0; mt < 4; ++mt) {
    f32x4 oacc = {0.f, 0.f, 0.f, 0.f};
#pragma unroll
    for (int q = 0; q < 4; ++q)
      oacc = __builtin_amdgcn_mfma_f32_16x16x32_bf16(
          op[(q * 64 + mt * 16 + col) * 4 + grp], nb[q], oacc, 0, 0, 0);
#pragma unroll
    for (int r = 0; r < 4; ++r)
      out[(mt * 16 + grp * 4 + r) * HW + p] = oacc[r];
  }
}

extern "C" void kernel_launch(void* const* d_in, const int* in_sizes, int n_in,
                              void* d_out, int out_size, void* d_ws, size_t ws_size,
                              hipStream_t stream) {
  const float* rgb  = (const float*)d_in[0];
  const float* ev   = (const float*)d_in[1];
  const float* cw   = (const float*)d_in[2];
  const float* g    = (const float*)d_in[3];
  const float* b    = (const float*)d_in[4];
  const float* w3   = (const float*)d_in[5];
  const float* df2  = (const float*)d_in[6];
  const float* spw  = (const float*)d_in[7];
  const float* outw = (const float*)d_in[8];
  float* out = (float*)d_out;
  char* wsb = (char*)d_ws;

  const size_t MB = 1u << 20;
  short* featT_rgb = (short*)(wsb);             // 4 MB
  short* featT_ev  = (short*)(wsb + 4 * MB);    // 4 MB
  short* rT_rgb    = (short*)(wsb + 8 * MB);    // 4 MB
  short* rT_ev     = (short*)(wsb + 12 * MB);   // 4 MB
  short* enT_rgb   = (short*)(wsb + 16 * MB);   // 4 MB
  short* enT_ev    = (short*)(wsb + 20 * MB);   // 4 MB
  short* xT_rgb    = (short*)(wsb + 24 * MB);   // 2 MB
  short* xT_ev     = (short*)(wsb + 26 * MB);   // 2 MB
  short* df2p      = (short*)(wsb + 28 * MB);   // 1 MB
  short* w3p       = (short*)(wsb + 29 * MB);   // 288 KB
  short* cwp       = (short*)(wsb + 30 * MB);   // 16 KB
  short* spwp      = (short*)(wsb + 31 * MB);   // 32 KB
  short* outwp     = (short*)(wsb + 32 * MB);   // 16 KB

  hipLaunchKernelGGL(k_prep_x, dim3(64, 1, 2), dim3(256), 0, stream,
                     rgb, ev, xT_rgb, xT_ev);
  hipLaunchKernelGGL(k_prep_cw, dim3(32), dim3(256), 0, stream, cw, cwp);
  hipLaunchKernelGGL(k_prep_w3, dim3(576), dim3(256), 0, stream, w3, w3p);
  hipLaunchKernelGGL(k_prep_df2, dim3(2048), dim3(256), 0, stream, df2, df2p);
  hipLaunchKernelGGL(k_prep_spw, dim3(64), dim3(256), 0, stream, spw, spwp);
  hipLaunchKernelGGL(k_prep_outw, dim3(32), dim3(256), 0, stream, outw, outwp);
  hipLaunchKernelGGL(k_feat_mfma, dim3(256, 1, 2), dim3(256), 0, stream,
                     xT_rgb, xT_ev, cwp, g, b, featT_rgb, featT_ev);
  hipLaunchKernelGGL(k_conv3_mfma, dim3(128, 1, 2), dim3(256), 0, stream,
                     featT_rgb, featT_ev, w3p, rT_rgb, rT_ev);
  hipLaunchKernelGGL(k_filt_v2, dim3(64, 8, 2), dim3(256), 0, stream,
                     featT_rgb, featT_ev, rT_rgb, rT_ev, df2p, enT_rgb, enT_ev);
  hipLaunchKernelGGL(k_post, dim3(256), dim3(256), 0, stream,
                     enT_rgb, enT_ev, featT_rgb, spwp, outwp, g, b, out);
}

// Round 5
// 158.691 us; speedup vs baseline: 11.9658x; 1.0143x over previous
//
#include <hip/hip_runtime.h>
#include <math.h>

#define HW 16384
#define WD 128
#define HD 128
#define CIN 64
#define CH 128
#define EPSV 1e-5f

typedef __attribute__((ext_vector_type(8))) short short8;
typedef __attribute__((ext_vector_type(4))) short short4v;
typedef __attribute__((ext_vector_type(4))) float f32x4;

__device__ __forceinline__ short f2bf(float x) {
  unsigned u = __float_as_uint(x);
  u += 0x7FFFu + ((u >> 16) & 1u);   // RNE
  return (short)(u >> 16);
}
__device__ __forceinline__ float bf2f(short x) {
  return __uint_as_float(((unsigned)(unsigned short)x) << 16);
}

// ---------------------------------------------------------------------------
// Prep: x [64][HW] fp32 -> xT [p][64] bf16
// ---------------------------------------------------------------------------
__global__ __launch_bounds__(256) void k_prep_x(const float* __restrict__ rgb,
                                                const float* __restrict__ ev,
                                                short* __restrict__ xT_rgb,
                                                short* __restrict__ xT_ev) {
  const float* x = blockIdx.z ? ev : rgb;
  short* xT = blockIdx.z ? xT_ev : xT_rgb;
  int p = blockIdx.x * 256 + threadIdx.x;
#pragma unroll
  for (int cb = 0; cb < 8; ++cb) {
    short8 v;
#pragma unroll
    for (int j = 0; j < 8; ++j) v[j] = f2bf(x[(cb * 8 + j) * HW + p]);
    *(short8*)(xT + p * CIN + cb * 8) = v;
  }
}

// ---------------------------------------------------------------------------
// Weight preps -> A-frag layout [q][m][grp4][j8] bf16
// ---------------------------------------------------------------------------
__global__ __launch_bounds__(256) void k_prep_cw(const float* __restrict__ cw,
                                                 short* __restrict__ cwp) {
  int idx = blockIdx.x * 256 + threadIdx.x;  // 8192: q2 x m128
  int j = idx & 7, grp = (idx >> 3) & 3, m = (idx >> 5) & 127, q = idx >> 12;
  cwp[idx] = f2bf(cw[m * CIN + q * 32 + grp * 8 + j]);
}

__global__ __launch_bounds__(256) void k_prep_w3(const float* __restrict__ w3,
                                                 short* __restrict__ w3p) {
  int idx = blockIdx.x * 256 + threadIdx.x;  // 147456: ks36 x m128
  int j = idx & 7, grp = (idx >> 3) & 3, m = (idx >> 5) & 127, ks = idx >> 12;
  int tap = ks >> 2, q = ks & 3;
  int c = q * 32 + grp * 8 + j;
  w3p[idx] = f2bf(w3[(m * CH + c) * 9 + tap]);
}

__global__ __launch_bounds__(256) void k_prep_df2(const float* __restrict__ df2,
                                                  short* __restrict__ df2p) {
  int idx = blockIdx.x * 256 + threadIdx.x;  // 524288: [c128][t32][k128]
  int c = idx >> 12, t = (idx >> 7) & 31, k = idx & 127;
  float v = (t < 25) ? df2[(c * 25 + t) * CH + k] : 0.f;
  df2p[idx] = f2bf(v);
}

__global__ __launch_bounds__(256) void k_prep_spw(const float* __restrict__ spw,
                                                  short* __restrict__ spwp) {
  int idx = blockIdx.x * 256 + threadIdx.x;  // 16384: q4 x m128
  int j = idx & 7, grp = (idx >> 3) & 3, m = (idx >> 5) & 127, q = idx >> 12;
  spwp[idx] = f2bf(spw[m * CH + q * 32 + grp * 8 + j]);
}

__global__ __launch_bounds__(256) void k_prep_outw(const float* __restrict__ outw,
                                                   short* __restrict__ outwp) {
  int idx = blockIdx.x * 256 + threadIdx.x;  // 8192: q4 x m64
  int j = idx & 7, grp = (idx >> 3) & 3, m = (idx >> 5) & 63, q = idx >> 11;
  outwp[idx] = f2bf(outw[m * CH + q * 32 + grp * 8 + j]);
}

// ---------------------------------------------------------------------------
// Kernel 1 (MFMA): featT = bf16(LN_c(conv1x1(x, cw)))  [p][128]
// ---------------------------------------------------------------------------
__global__ __launch_bounds__(256) void k_feat_mfma(
    const short* __restrict__ xT_rgb, const short* __restrict__ xT_ev,
    const short* __restrict__ cwp, const float* __restrict__ g,
    const float* __restrict__ b,
    short* __restrict__ featT_rgb, short* __restrict__ featT_ev) {
  __shared__ float sg[CH], sb[CH];
  int tid = threadIdx.x;
  if (tid < CH) { sg[tid] = g[tid]; sb[tid] = b[tid]; }
  __syncthreads();
  const short* xT = blockIdx.z ? xT_ev : xT_rgb;
  short* featT = blockIdx.z ? featT_ev : featT_rgb;
  int wave = tid >> 6, lane = tid & 63, col = lane & 15, grp = lane >> 4;
  int p = blockIdx.x * 64 + wave * 16 + col;

  const short8* bp = (const short8*)(xT + p * CIN);
  short8 bq0 = bp[grp], bq1 = bp[4 + grp];
  const short8* ap = (const short8*)cwp;

  f32x4 acc[8];
#pragma unroll
  for (int mt = 0; mt < 8; ++mt) {
    acc[mt] = (f32x4){0.f, 0.f, 0.f, 0.f};
    short8 a0 = ap[(0 * 128 + mt * 16 + col) * 4 + grp];
    short8 a1 = ap[(1 * 128 + mt * 16 + col) * 4 + grp];
    acc[mt] = __builtin_amdgcn_mfma_f32_16x16x32_bf16(a0, bq0, acc[mt], 0, 0, 0);
    acc[mt] = __builtin_amdgcn_mfma_f32_16x16x32_bf16(a1, bq1, acc[mt], 0, 0, 0);
  }
  float s = 0.f, s2 = 0.f;
#pragma unroll
  for (int mt = 0; mt < 8; ++mt)
#pragma unroll
    for (int r = 0; r < 4; ++r) { float v = acc[mt][r]; s += v; s2 += v * v; }
  s += __shfl_xor(s, 16);  s += __shfl_xor(s, 32);
  s2 += __shfl_xor(s2, 16); s2 += __shfl_xor(s2, 32);
  float mean = s * (1.f / CH);
  float var = s2 * (1.f / CH) - mean * mean;
  float rinv = rsqrtf(var + EPSV);
#pragma unroll
  for (int mt = 0; mt < 8; ++mt) {
    short4v fv;
#pragma unroll
    for (int r = 0; r < 4; ++r) {
      int m = mt * 16 + grp * 4 + r;
      fv[r] = f2bf((acc[mt][r] - mean) * rinv * sg[m] + sb[m]);
    }
    *(short4v*)(featT + p * CH + mt * 16 + grp * 4) = fv;
  }
}

// ---------------------------------------------------------------------------
// Kernel 2 (MFMA): rT = bf16(relu(conv3x3(featT, df1_w))), implicit im2col.
// v2: m split across wave pairs -> 512 blocks / 2048 waves (2 waves/SIMD).
// Wave = 2 rows x 16 cols x 64 m (mh = wave&1).
// ---------------------------------------------------------------------------
__global__ __launch_bounds__(256) void k_conv3_v2(
    const short* __restrict__ featT_rgb, const short* __restrict__ featT_ev,
    const short* __restrict__ w3p,
    short* __restrict__ rT_rgb, short* __restrict__ rT_ev) {
  const short* featT = blockIdx.z ? featT_ev : featT_rgb;
  short* rT = blockIdx.z ? rT_ev : rT_rgb;
  int tid = threadIdx.x, wave = tid >> 6, lane = tid & 63;
  int col = lane & 15, grp = lane >> 4;
  int mh = wave & 1;                       // m-half
  int ty = (blockIdx.x >> 3) * 4 + (wave >> 1) * 2;
  int tx = (blockIdx.x & 7) * 16;
  int x = tx + col;

  f32x4 acc[2][4];
#pragma unroll
  for (int s = 0; s < 2; ++s)
#pragma unroll
    for (int mt = 0; mt < 4; ++mt) acc[s][mt] = (f32x4){0.f, 0.f, 0.f, 0.f};

  const short8* ap = (const short8*)w3p;
  for (int ks = 0; ks < 36; ++ks) {
    int tap = ks >> 2, q = ks & 3;
    int dy = tap / 3 - 1, dx = tap % 3 - 1;
    int xs = x + dx;
    bool xok = (unsigned)xs < (unsigned)WD;
    int y0 = ty + dy, y1 = ty + 1 + dy;
    short8 b0 = {0, 0, 0, 0, 0, 0, 0, 0}, b1 = {0, 0, 0, 0, 0, 0, 0, 0};
    if (xok && (unsigned)y0 < (unsigned)HD)
      b0 = *(const short8*)(featT + (y0 * WD + xs) * CH + q * 32 + grp * 8);
    if (xok && (unsigned)y1 < (unsigned)HD)
      b1 = *(const short8*)(featT + (y1 * WD + xs) * CH + q * 32 + grp * 8);
#pragma unroll
    for (int mt = 0; mt < 4; ++mt) {
      short8 a = ap[(ks * 128 + (mh * 4 + mt) * 16 + col) * 4 + grp];
      acc[0][mt] = __builtin_amdgcn_mfma_f32_16x16x32_bf16(a, b0, acc[0][mt], 0, 0, 0);
      acc[1][mt] = __builtin_amdgcn_mfma_f32_16x16x32_bf16(a, b1, acc[1][mt], 0, 0, 0);
    }
  }
#pragma unroll
  for (int s = 0; s < 2; ++s) {
    int p = (ty + s) * WD + x;
#pragma unroll
    for (int mt = 0; mt < 4; ++mt) {
      short4v v;
#pragma unroll
      for (int r = 0; r < 4; ++r) v[r] = f2bf(fmaxf(acc[s][mt][r], 0.f));
      *(short4v*)(rT + p * CH + (mh * 4 + mt) * 16 + grp * 4) = v;
    }
  }
}

// ---------------------------------------------------------------------------
// Kernel 3: fused dynamic-filter gen + 5x5 apply, v3.
// c-chunk 8 (grid.y=16 -> 2048 blocks), software-pipelined A prefetch:
// A(c+1) global loads issued BEFORE MFMA+epilogue of c (fully unrolled).
// fw tail padded+zeroed so tap>=25 epilogue reads are in-bounds finite.
// ---------------------------------------------------------------------------
__global__ __launch_bounds__(256) void k_filt_v3(
    const short* __restrict__ featT_rgb, const short* __restrict__ featT_ev,
    const short* __restrict__ rT_rgb, const short* __restrict__ rT_ev,
    const short* __restrict__ df2p,
    short* __restrict__ enT_rgb, short* __restrict__ enT_ev) {
  __shared__ float fw[8 * 400 + 64];   // 13.1 KB (tail pad for tap>=25 reads)
  const short* featT = blockIdx.z ? featT_ev : featT_rgb;
  const short* rT = blockIdx.z ? rT_ev : rT_rgb;
  short* enT = blockIdx.z ? enT_ev : enT_rgb;
  int tid = threadIdx.x;
  int wave = tid >> 6, lane = tid & 63;
  int col = lane & 15, grp = lane >> 4;
  int ty0 = (blockIdx.x >> 3) * 16, tx0 = (blockIdx.x & 7) * 16;
  int c0 = blockIdx.y * 8;
  int py0 = ty0 + wave * 4;
  int pxx = tx0 + col;

  // stage zero-padded window rows ty0-2..ty0+17, cols tx0-2..tx0+17
  for (int px = tid; px < 400; px += 256) {
    int wr = px / 20, wc = px % 20;
    int y = ty0 + wr - 2, x = tx0 + wc - 2;
    short8 v = {0, 0, 0, 0, 0, 0, 0, 0};
    if ((unsigned)y < (unsigned)HD && (unsigned)x < (unsigned)WD)
      v = *(const short8*)(featT + (y * WD + x) * CH + c0);
#pragma unroll
    for (int ci = 0; ci < 8; ++ci) fw[ci * 400 + px] = bf2f(v[ci]);
  }
  if (tid < 64) fw[8 * 400 + tid] = 0.f;   // finite tail

  // B fragments (resident for whole c-loop)
  short8 rv[4][4];
#pragma unroll
  for (int s = 0; s < 4; ++s) {
    const short8* bp = (const short8*)(rT + ((py0 + s) * WD + pxx) * CH);
#pragma unroll
    for (int q = 0; q < 4; ++q) rv[s][q] = bp[q * 4 + grp];
  }

  // epilogue LDS indices (add s*20 at use)
  int idx0[4], idx1[4];
#pragma unroll
  for (int r = 0; r < 4; ++r) {
    int tap0 = grp * 4 + r;
    int tap1 = 16 + grp * 4 + r;
    idx0[r] = (wave * 4 + tap0 / 5) * 20 + col + tap0 % 5;
    idx1[r] = (wave * 4 + tap1 / 5) * 20 + col + tap1 % 5;
  }
  __syncthreads();

  const short8* apb = (const short8*)df2p;
  short8 A0[8], A1[8];
  {
    const short8* ap = apb + (size_t)c0 * 512;
#pragma unroll
    for (int q = 0; q < 4; ++q) {
      A0[q] = ap[col * 16 + q * 4 + grp];
      A0[4 + q] = ap[(16 + col) * 16 + q * 4 + grp];
    }
  }
#pragma unroll
  for (int c = 0; c < 8; ++c) {
    if (c < 7) {   // prefetch next channel's A-frags (overlaps MFMA+epilogue)
      const short8* ap = apb + (size_t)(c0 + c + 1) * 512;
#pragma unroll
      for (int q = 0; q < 4; ++q) {
        A1[q] = ap[col * 16 + q * 4 + grp];
        A1[4 + q] = ap[(16 + col) * 16 + q * 4 + grp];
      }
    }
    const float* fwc = fw + c * 400;
#pragma unroll
    for (int s = 0; s < 4; ++s) {
      f32x4 acc0 = {0.f, 0.f, 0.f, 0.f}, acc1 = {0.f, 0.f, 0.f, 0.f};
#pragma unroll
      for (int q = 0; q < 4; ++q) {
        acc0 = __builtin_amdgcn_mfma_f32_16x16x32_bf16(A0[q], rv[s][q], acc0, 0, 0, 0);
        acc1 = __builtin_amdgcn_mfma_f32_16x16x32_bf16(A0[4 + q], rv[s][q], acc1, 0, 0, 0);
      }
      float partial = 0.f;
#pragma unroll
      for (int r = 0; r < 4; ++r) {
        partial += fwc[idx0[r] + s * 20] * acc0[r];
        partial += fwc[idx1[r] + s * 20] * acc1[r];
      }
      partial += __shfl_xor(partial, 16);
      partial += __shfl_xor(partial, 32);
      if (lane < 16) enT[((py0 + s) * WD + pxx) * CH + c0 + c] = f2bf(partial);
    }
#pragma unroll
    for (int q = 0; q < 8; ++q) A0[q] = A1[q];
  }
}

// ---------------------------------------------------------------------------
// Kernel 4 (fused k_fuse + LN + k_out, all MFMA):
// ---------------------------------------------------------------------------
__global__ __launch_bounds__(256) void k_post(
    const short* __restrict__ enT_rgb, const short* __restrict__ enT_ev,
    const short* __restrict__ featT_rgb,
    const short* __restrict__ spwp, const short* __restrict__ outwp,
    const float* __restrict__ g, const float* __restrict__ b,
    float* __restrict__ out) {
  __shared__ short nlds[4][16 * 136];   // 17.4 KB
  __shared__ float sg[CH], sb[CH];
  int tid = threadIdx.x;
  if (tid < CH) { sg[tid] = g[tid]; sb[tid] = b[tid]; }
  __syncthreads();
  int wave = tid >> 6, lane = tid & 63, col = lane & 15, grp = lane >> 4;
  int p = blockIdx.x * 64 + wave * 16 + col;

  // gate GEMM: z[128 o][16 px] = sp_w @ en_ev
  const short8* bp = (const short8*)(enT_ev + p * CH);
  short8 bq[4];
#pragma unroll
  for (int q = 0; q < 4; ++q) bq[q] = bp[q * 4 + grp];
  const short8* ap = (const short8*)spwp;
  f32x4 z[8];
#pragma unroll
  for (int mt = 0; mt < 8; ++mt) {
    z[mt] = (f32x4){0.f, 0.f, 0.f, 0.f};
#pragma unroll
    for (int q = 0; q < 4; ++q)
      z[mt] = __builtin_amdgcn_mfma_f32_16x16x32_bf16(
          ap[(q * 128 + mt * 16 + col) * 4 + grp], bq[q], z[mt], 0, 0, 0);
  }

  // fused + LN stats
  const short4v* er = (const short4v*)(enT_rgb + p * CH);
  const short4v* fr = (const short4v*)(featT_rgb + p * CH);
  float fused[8][4];
  float s = 0.f, s2 = 0.f;
#pragma unroll
  for (int mt = 0; mt < 8; ++mt) {
    short4v e4 = er[mt * 4 + grp];
    short4v f4 = fr[mt * 4 + grp];
#pragma unroll
    for (int r = 0; r < 4; ++r) {
      float sig = 1.f / (1.f + __expf(-z[mt][r]));
      float f = bf2f(e4[r]) * (1.f + sig) + bf2f(f4[r]);
      fused[mt][r] = f; s += f; s2 += f * f;
    }
  }
  s += __shfl_xor(s, 16);  s += __shfl_xor(s, 32);
  s2 += __shfl_xor(s2, 16); s2 += __shfl_xor(s2, 32);
  float mean = s * (1.f / CH);
  float var = s2 * (1.f / CH) - mean * mean;
  float rinv = rsqrtf(var + EPSV);

  // normalize -> bf16 -> LDS [px][o] (stride 136)
  short* nl = &nlds[wave][0];
#pragma unroll
  for (int mt = 0; mt < 8; ++mt) {
    short4v nv;
#pragma unroll
    for (int r = 0; r < 4; ++r) {
      int o = mt * 16 + grp * 4 + r;
      nv[r] = f2bf((fused[mt][r] - mean) * rinv * sg[o] + sb[o]);
    }
    *(short4v*)(nl + col * 136 + mt * 16 + grp * 4) = nv;
  }

  // out GEMM: out[64 o][16 px] = out_w @ norm
  short8 nb[4];
#pragma unroll
  for (int q = 0; q < 4; ++q)
    nb[q] = *(const short8*)(nl + col * 136 + q * 32 + grp * 8);
  const short8* op = (const short8*)outwp;
#pragma unroll
  for (int mt = 0; mt < 4; ++mt) {
    f32x4 oacc = {0.f, 0.f, 0.f, 0.f};
#pragma unroll
    for (int q = 0; q < 4; ++q)
      oacc = __builtin_amdgcn_mfma_f32_16x16x32_bf16(
          op[(q * 64 + mt * 16 + col) * 4 + grp], nb[q], oacc, 0, 0, 0);
#pragma unroll
    for (int r = 0; r < 4; ++r)
      out[(mt * 16 + grp * 4 + r) * HW + p] = oacc[r];
  }
}

extern "C" void kernel_launch(void* const* d_in, const int* in_sizes, int n_in,
                              void* d_out, int out_size, void* d_ws, size_t ws_size,
                              hipStream_t stream) {
  const float* rgb  = (const float*)d_in[0];
  const float* ev   = (const float*)d_in[1];
  const float* cw   = (const float*)d_in[2];
  const float* g    = (const float*)d_in[3];
  const float* b    = (const float*)d_in[4];
  const float* w3   = (const float*)d_in[5];
  const float* df2  = (const float*)d_in[6];
  const float* spw  = (const float*)d_in[7];
  const float* outw = (const float*)d_in[8];
  float* out = (float*)d_out;
  char* wsb = (char*)d_ws;

  const size_t MB = 1u << 20;
  short* featT_rgb = (short*)(wsb);             // 4 MB
  short* featT_ev  = (short*)(wsb + 4 * MB);    // 4 MB
  short* rT_rgb    = (short*)(wsb + 8 * MB);    // 4 MB
  short* rT_ev     = (short*)(wsb + 12 * MB);   // 4 MB
  short* enT_rgb   = (short*)(wsb + 16 * MB);   // 4 MB
  short* enT_ev    = (short*)(wsb + 20 * MB);   // 4 MB
  short* xT_rgb    = (short*)(wsb + 24 * MB);   // 2 MB
  short* xT_ev     = (short*)(wsb + 26 * MB);   // 2 MB
  short* df2p      = (short*)(wsb + 28 * MB);   // 1 MB
  short* w3p       = (short*)(wsb + 29 * MB);   // 288 KB
  short* cwp       = (short*)(wsb + 30 * MB);   // 16 KB
  short* spwp      = (short*)(wsb + 31 * MB);   // 32 KB
  short* outwp     = (short*)(wsb + 32 * MB);   // 16 KB

  hipLaunchKernelGGL(k_prep_x, dim3(64, 1, 2), dim3(256), 0, stream,
                     rgb, ev, xT_rgb, xT_ev);
  hipLaunchKernelGGL(k_prep_cw, dim3(32), dim3(256), 0, stream, cw, cwp);
  hipLaunchKernelGGL(k_prep_w3, dim3(576), dim3(256), 0, stream, w3, w3p);
  hipLaunchKernelGGL(k_prep_df2, dim3(2048), dim3(256), 0, stream, df2, df2p);
  hipLaunchKernelGGL(k_prep_spw, dim3(64), dim3(256), 0, stream, spw, spwp);
  hipLaunchKernelGGL(k_prep_outw, dim3(32), dim3(256), 0, stream, outw, outwp);
  hipLaunchKernelGGL(k_feat_mfma, dim3(256, 1, 2), dim3(256), 0, stream,
                     xT_rgb, xT_ev, cwp, g, b, featT_rgb, featT_ev);
  hipLaunchKernelGGL(k_conv3_v2, dim3(256, 1, 2), dim3(256), 0, stream,
                     featT_rgb, featT_ev, w3p, rT_rgb, rT_ev);
  hipLaunchKernelGGL(k_filt_v3, dim3(64, 16, 2), dim3(256), 0, stream,
                     featT_rgb, featT_ev, rT_rgb, rT_ev, df2p, enT_rgb, enT_ev);
  hipLaunchKernelGGL(k_post, dim3(256), dim3(256), 0, stream,
                     enT_rgb, enT_ev, featT_rgb, spwp, outwp, g, b, out);
}

// Round 6
// 156.766 us; speedup vs baseline: 12.1127x; 1.0123x over previous
//
#include <hip/hip_runtime.h>
#include <math.h>

#define HW 16384
#define WD 128
#define HD 128
#define CIN 64
#define CH 128
#define EPSV 1e-5f

typedef __attribute__((ext_vector_type(8))) short short8;
typedef __attribute__((ext_vector_type(4))) short short4v;
typedef __attribute__((ext_vector_type(4))) float f32x4;

__device__ __forceinline__ short f2bf(float x) {
  unsigned u = __float_as_uint(x);
  u += 0x7FFFu + ((u >> 16) & 1u);   // RNE
  return (short)(u >> 16);
}
__device__ __forceinline__ float bf2f(short x) {
  return __uint_as_float(((unsigned)(unsigned short)x) << 16);
}

// ---------------------------------------------------------------------------
// Prep: x [64][HW] fp32 -> xT [p][64] bf16
// ---------------------------------------------------------------------------
__global__ __launch_bounds__(256) void k_prep_x(const float* __restrict__ rgb,
                                                const float* __restrict__ ev,
                                                short* __restrict__ xT_rgb,
                                                short* __restrict__ xT_ev) {
  const float* x = blockIdx.z ? ev : rgb;
  short* xT = blockIdx.z ? xT_ev : xT_rgb;
  int p = blockIdx.x * 256 + threadIdx.x;
#pragma unroll
  for (int cb = 0; cb < 8; ++cb) {
    short8 v;
#pragma unroll
    for (int j = 0; j < 8; ++j) v[j] = f2bf(x[(cb * 8 + j) * HW + p]);
    *(short8*)(xT + p * CIN + cb * 8) = v;
  }
}

// ---------------------------------------------------------------------------
// Weight preps -> A-frag layout [q][m][grp4][j8] bf16
// ---------------------------------------------------------------------------
__global__ __launch_bounds__(256) void k_prep_cw(const float* __restrict__ cw,
                                                 short* __restrict__ cwp) {
  int idx = blockIdx.x * 256 + threadIdx.x;  // 8192: q2 x m128
  int j = idx & 7, grp = (idx >> 3) & 3, m = (idx >> 5) & 127, q = idx >> 12;
  cwp[idx] = f2bf(cw[m * CIN + q * 32 + grp * 8 + j]);
}

__global__ __launch_bounds__(256) void k_prep_w3(const float* __restrict__ w3,
                                                 short* __restrict__ w3p) {
  int idx = blockIdx.x * 256 + threadIdx.x;  // 147456: ks36 x m128
  int j = idx & 7, grp = (idx >> 3) & 3, m = (idx >> 5) & 127, ks = idx >> 12;
  int tap = ks >> 2, q = ks & 3;
  int c = q * 32 + grp * 8 + j;
  w3p[idx] = f2bf(w3[(m * CH + c) * 9 + tap]);
}

__global__ __launch_bounds__(256) void k_prep_df2(const float* __restrict__ df2,
                                                  short* __restrict__ df2p) {
  int idx = blockIdx.x * 256 + threadIdx.x;  // 524288: [c128][t32][k128]
  int c = idx >> 12, t = (idx >> 7) & 31, k = idx & 127;
  float v = (t < 25) ? df2[(c * 25 + t) * CH + k] : 0.f;
  df2p[idx] = f2bf(v);
}

__global__ __launch_bounds__(256) void k_prep_spw(const float* __restrict__ spw,
                                                  short* __restrict__ spwp) {
  int idx = blockIdx.x * 256 + threadIdx.x;  // 16384: q4 x m128
  int j = idx & 7, grp = (idx >> 3) & 3, m = (idx >> 5) & 127, q = idx >> 12;
  spwp[idx] = f2bf(spw[m * CH + q * 32 + grp * 8 + j]);
}

__global__ __launch_bounds__(256) void k_prep_outw(const float* __restrict__ outw,
                                                   short* __restrict__ outwp) {
  int idx = blockIdx.x * 256 + threadIdx.x;  // 8192: q4 x m64
  int j = idx & 7, grp = (idx >> 3) & 3, m = (idx >> 5) & 63, q = idx >> 11;
  outwp[idx] = f2bf(outw[m * CH + q * 32 + grp * 8 + j]);
}

// ---------------------------------------------------------------------------
// Kernel 1 (MFMA): featT = bf16(LN_c(conv1x1(x, cw)))  [p][128]
// ---------------------------------------------------------------------------
__global__ __launch_bounds__(256) void k_feat_mfma(
    const short* __restrict__ xT_rgb, const short* __restrict__ xT_ev,
    const short* __restrict__ cwp, const float* __restrict__ g,
    const float* __restrict__ b,
    short* __restrict__ featT_rgb, short* __restrict__ featT_ev) {
  __shared__ float sg[CH], sb[CH];
  int tid = threadIdx.x;
  if (tid < CH) { sg[tid] = g[tid]; sb[tid] = b[tid]; }
  __syncthreads();
  const short* xT = blockIdx.z ? xT_ev : xT_rgb;
  short* featT = blockIdx.z ? featT_ev : featT_rgb;
  int wave = tid >> 6, lane = tid & 63, col = lane & 15, grp = lane >> 4;
  int p = blockIdx.x * 64 + wave * 16 + col;

  const short8* bp = (const short8*)(xT + p * CIN);
  short8 bq0 = bp[grp], bq1 = bp[4 + grp];
  const short8* ap = (const short8*)cwp;

  f32x4 acc[8];
#pragma unroll
  for (int mt = 0; mt < 8; ++mt) {
    acc[mt] = (f32x4){0.f, 0.f, 0.f, 0.f};
    short8 a0 = ap[(0 * 128 + mt * 16 + col) * 4 + grp];
    short8 a1 = ap[(1 * 128 + mt * 16 + col) * 4 + grp];
    acc[mt] = __builtin_amdgcn_mfma_f32_16x16x32_bf16(a0, bq0, acc[mt], 0, 0, 0);
    acc[mt] = __builtin_amdgcn_mfma_f32_16x16x32_bf16(a1, bq1, acc[mt], 0, 0, 0);
  }
  float s = 0.f, s2 = 0.f;
#pragma unroll
  for (int mt = 0; mt < 8; ++mt)
#pragma unroll
    for (int r = 0; r < 4; ++r) { float v = acc[mt][r]; s += v; s2 += v * v; }
  s += __shfl_xor(s, 16);  s += __shfl_xor(s, 32);
  s2 += __shfl_xor(s2, 16); s2 += __shfl_xor(s2, 32);
  float mean = s * (1.f / CH);
  float var = s2 * (1.f / CH) - mean * mean;
  float rinv = rsqrtf(var + EPSV);
#pragma unroll
  for (int mt = 0; mt < 8; ++mt) {
    short4v fv;
#pragma unroll
    for (int r = 0; r < 4; ++r) {
      int m = mt * 16 + grp * 4 + r;
      fv[r] = f2bf((acc[mt][r] - mean) * rinv * sg[m] + sb[m]);
    }
    *(short4v*)(featT + p * CH + mt * 16 + grp * 4) = fv;
  }
}

// ---------------------------------------------------------------------------
// Kernel 2 (MFMA): rT = bf16(relu(conv3x3(featT, df1_w))), implicit im2col.
// ---------------------------------------------------------------------------
__global__ __launch_bounds__(256) void k_conv3_v2(
    const short* __restrict__ featT_rgb, const short* __restrict__ featT_ev,
    const short* __restrict__ w3p,
    short* __restrict__ rT_rgb, short* __restrict__ rT_ev) {
  const short* featT = blockIdx.z ? featT_ev : featT_rgb;
  short* rT = blockIdx.z ? rT_ev : rT_rgb;
  int tid = threadIdx.x, wave = tid >> 6, lane = tid & 63;
  int col = lane & 15, grp = lane >> 4;
  int mh = wave & 1;                       // m-half
  int ty = (blockIdx.x >> 3) * 4 + (wave >> 1) * 2;
  int tx = (blockIdx.x & 7) * 16;
  int x = tx + col;

  f32x4 acc[2][4];
#pragma unroll
  for (int s = 0; s < 2; ++s)
#pragma unroll
    for (int mt = 0; mt < 4; ++mt) acc[s][mt] = (f32x4){0.f, 0.f, 0.f, 0.f};

  const short8* ap = (const short8*)w3p;
  for (int ks = 0; ks < 36; ++ks) {
    int tap = ks >> 2, q = ks & 3;
    int dy = tap / 3 - 1, dx = tap % 3 - 1;
    int xs = x + dx;
    bool xok = (unsigned)xs < (unsigned)WD;
    int y0 = ty + dy, y1 = ty + 1 + dy;
    short8 b0 = {0, 0, 0, 0, 0, 0, 0, 0}, b1 = {0, 0, 0, 0, 0, 0, 0, 0};
    if (xok && (unsigned)y0 < (unsigned)HD)
      b0 = *(const short8*)(featT + (y0 * WD + xs) * CH + q * 32 + grp * 8);
    if (xok && (unsigned)y1 < (unsigned)HD)
      b1 = *(const short8*)(featT + (y1 * WD + xs) * CH + q * 32 + grp * 8);
#pragma unroll
    for (int mt = 0; mt < 4; ++mt) {
      short8 a = ap[(ks * 128 + (mh * 4 + mt) * 16 + col) * 4 + grp];
      acc[0][mt] = __builtin_amdgcn_mfma_f32_16x16x32_bf16(a, b0, acc[0][mt], 0, 0, 0);
      acc[1][mt] = __builtin_amdgcn_mfma_f32_16x16x32_bf16(a, b1, acc[1][mt], 0, 0, 0);
    }
  }
#pragma unroll
  for (int s = 0; s < 2; ++s) {
    int p = (ty + s) * WD + x;
#pragma unroll
    for (int mt = 0; mt < 4; ++mt) {
      short4v v;
#pragma unroll
      for (int r = 0; r < 4; ++r) v[r] = f2bf(fmaxf(acc[s][mt][r], 0.f));
      *(short4v*)(rT + p * CH + (mh * 4 + mt) * 16 + grp * 4) = v;
    }
  }
}

// ---------------------------------------------------------------------------
// Kernel 3: fused dynamic-filter gen + 5x5 apply, v5.
// Per c: ALL 32 MFMAs first (acc for 4 s live), then batched epilogue:
// 32 ds_reads issued together (ILP), 4 parallel shfl chains, single
// full-wave store (s selected by grp via cndmask). A double-buffered.
// ---------------------------------------------------------------------------
__global__ __launch_bounds__(256, 2) void k_filt_v5(
    const short* __restrict__ featT_rgb, const short* __restrict__ featT_ev,
    const short* __restrict__ rT_rgb, const short* __restrict__ rT_ev,
    const short* __restrict__ df2p,
    short* __restrict__ enT_rgb, short* __restrict__ enT_ev) {
  __shared__ float fw[8 * 400 + 64];   // 13.1 KB (tail pad for tap>=25 reads)
  const short* featT = blockIdx.z ? featT_ev : featT_rgb;
  const short* rT = blockIdx.z ? rT_ev : rT_rgb;
  short* enT = blockIdx.z ? enT_ev : enT_rgb;
  int tid = threadIdx.x;
  int wave = tid >> 6, lane = tid & 63;
  int col = lane & 15, grp = lane >> 4;
  int ty0 = (blockIdx.x >> 3) * 16, tx0 = (blockIdx.x & 7) * 16;
  int c0 = blockIdx.y * 8;
  int py0 = ty0 + wave * 4;
  int pxx = tx0 + col;

  // stage zero-padded window rows ty0-2..ty0+17, cols tx0-2..tx0+17
  for (int px = tid; px < 400; px += 256) {
    int wr = px / 20, wc = px % 20;
    int y = ty0 + wr - 2, x = tx0 + wc - 2;
    short8 v = {0, 0, 0, 0, 0, 0, 0, 0};
    if ((unsigned)y < (unsigned)HD && (unsigned)x < (unsigned)WD)
      v = *(const short8*)(featT + (y * WD + x) * CH + c0);
#pragma unroll
    for (int ci = 0; ci < 8; ++ci) fw[ci * 400 + px] = bf2f(v[ci]);
  }
  if (tid < 64) fw[8 * 400 + tid] = 0.f;   // finite tail

  // B fragments (resident for whole c-loop)
  short8 rv[4][4];
#pragma unroll
  for (int s = 0; s < 4; ++s) {
    const short8* bp = (const short8*)(rT + ((py0 + s) * WD + pxx) * CH);
#pragma unroll
    for (int q = 0; q < 4; ++q) rv[s][q] = bp[q * 4 + grp];
  }

  // epilogue LDS indices (add s*20 at use)
  int idx0[4], idx1[4];
#pragma unroll
  for (int r = 0; r < 4; ++r) {
    int tap0 = grp * 4 + r;
    int tap1 = 16 + grp * 4 + r;
    idx0[r] = (wave * 4 + tap0 / 5) * 20 + col + tap0 % 5;
    idx1[r] = (wave * 4 + tap1 / 5) * 20 + col + tap1 % 5;
  }
  __syncthreads();

  const short8* apb = (const short8*)df2p;
  short8 A0[8], A1[8];
  {
    const short8* ap = apb + (size_t)c0 * 512;
#pragma unroll
    for (int q = 0; q < 4; ++q) {
      A0[q] = ap[col * 16 + q * 4 + grp];
      A0[4 + q] = ap[(16 + col) * 16 + q * 4 + grp];
    }
  }
  // store base: all 64 lanes store row (py0+grp), col pxx
  short* stp = enT + ((py0 + grp) * WD + pxx) * CH + c0;

#pragma unroll
  for (int c = 0; c < 8; ++c) {
    if (c < 7) {   // prefetch next channel's A-frags
      const short8* ap = apb + (size_t)(c0 + c + 1) * 512;
#pragma unroll
      for (int q = 0; q < 4; ++q) {
        A1[q] = ap[col * 16 + q * 4 + grp];
        A1[4 + q] = ap[(16 + col) * 16 + q * 4 + grp];
      }
    }
    // phase 1: all MFMAs for this c (4 s-subtiles)
    f32x4 acc0[4], acc1[4];
#pragma unroll
    for (int s = 0; s < 4; ++s) {
      acc0[s] = (f32x4){0.f, 0.f, 0.f, 0.f};
      acc1[s] = (f32x4){0.f, 0.f, 0.f, 0.f};
#pragma unroll
      for (int q = 0; q < 4; ++q) {
        acc0[s] = __builtin_amdgcn_mfma_f32_16x16x32_bf16(A0[q], rv[s][q], acc0[s], 0, 0, 0);
        acc1[s] = __builtin_amdgcn_mfma_f32_16x16x32_bf16(A0[4 + q], rv[s][q], acc1[s], 0, 0, 0);
      }
    }
    // phase 2: batched epilogue (reads pipelined, 4 parallel shfl chains)
    const float* fwc = fw + c * 400;
    float part[4];
#pragma unroll
    for (int s = 0; s < 4; ++s) {
      float p = 0.f;
#pragma unroll
      for (int r = 0; r < 4; ++r) {
        p += fwc[idx0[r] + s * 20] * acc0[s][r];
        p += fwc[idx1[r] + s * 20] * acc1[s][r];
      }
      part[s] = p;
    }
#pragma unroll
    for (int s = 0; s < 4; ++s) part[s] += __shfl_xor(part[s], 16);
#pragma unroll
    for (int s = 0; s < 4; ++s) part[s] += __shfl_xor(part[s], 32);
    float val = (grp == 0) ? part[0] : (grp == 1) ? part[1]
              : (grp == 2) ? part[2] : part[3];
    stp[c] = f2bf(val);
#pragma unroll
    for (int q = 0; q < 8; ++q) A0[q] = A1[q];
  }
}

// ---------------------------------------------------------------------------
// Kernel 4 (fused k_fuse + LN + k_out, all MFMA):
// ---------------------------------------------------------------------------
__global__ __launch_bounds__(256) void k_post(
    const short* __restrict__ enT_rgb, const short* __restrict__ enT_ev,
    const short* __restrict__ featT_rgb,
    const short* __restrict__ spwp, const short* __restrict__ outwp,
    const float* __restrict__ g, const float* __restrict__ b,
    float* __restrict__ out) {
  __shared__ short nlds[4][16 * 136];   // 17.4 KB
  __shared__ float sg[CH], sb[CH];
  int tid = threadIdx.x;
  if (tid < CH) { sg[tid] = g[tid]; sb[tid] = b[tid]; }
  __syncthreads();
  int wave = tid >> 6, lane = tid & 63, col = lane & 15, grp = lane >> 4;
  int p = blockIdx.x * 64 + wave * 16 + col;

  // gate GEMM: z[128 o][16 px] = sp_w @ en_ev
  const short8* bp = (const short8*)(enT_ev + p * CH);
  short8 bq[4];
#pragma unroll
  for (int q = 0; q < 4; ++q) bq[q] = bp[q * 4 + grp];
  const short8* ap = (const short8*)spwp;
  f32x4 z[8];
#pragma unroll
  for (int mt = 0; mt < 8; ++mt) {
    z[mt] = (f32x4){0.f, 0.f, 0.f, 0.f};
#pragma unroll
    for (int q = 0; q < 4; ++q)
      z[mt] = __builtin_amdgcn_mfma_f32_16x16x32_bf16(
          ap[(q * 128 + mt * 16 + col) * 4 + grp], bq[q], z[mt], 0, 0, 0);
  }

  // fused + LN stats
  const short4v* er = (const short4v*)(enT_rgb + p * CH);
  const short4v* fr = (const short4v*)(featT_rgb + p * CH);
  float fused[8][4];
  float s = 0.f, s2 = 0.f;
#pragma unroll
  for (int mt = 0; mt < 8; ++mt) {
    short4v e4 = er[mt * 4 + grp];
    short4v f4 = fr[mt * 4 + grp];
#pragma unroll
    for (int r = 0; r < 4; ++r) {
      float sig = 1.f / (1.f + __expf(-z[mt][r]));
      float f = bf2f(e4[r]) * (1.f + sig) + bf2f(f4[r]);
      fused[mt][r] = f; s += f; s2 += f * f;
    }
  }
  s += __shfl_xor(s, 16);  s += __shfl_xor(s, 32);
  s2 += __shfl_xor(s2, 16); s2 += __shfl_xor(s2, 32);
  float mean = s * (1.f / CH);
  float var = s2 * (1.f / CH) - mean * mean;
  float rinv = rsqrtf(var + EPSV);

  // normalize -> bf16 -> LDS [px][o] (stride 136)
  short* nl = &nlds[wave][0];
#pragma unroll
  for (int mt = 0; mt < 8; ++mt) {
    short4v nv;
#pragma unroll
    for (int r = 0; r < 4; ++r) {
      int o = mt * 16 + grp * 4 + r;
      nv[r] = f2bf((fused[mt][r] - mean) * rinv * sg[o] + sb[o]);
    }
    *(short4v*)(nl + col * 136 + mt * 16 + grp * 4) = nv;
  }

  // out GEMM: out[64 o][16 px] = out_w @ norm
  short8 nb[4];
#pragma unroll
  for (int q = 0; q < 4; ++q)
    nb[q] = *(const short8*)(nl + col * 136 + q * 32 + grp * 8);
  const short8* op = (const short8*)outwp;
#pragma unroll
  for (int mt = 0; mt < 4; ++mt) {
    f32x4 oacc = {0.f, 0.f, 0.f, 0.f};
#pragma unroll
    for (int q = 0; q < 4; ++q)
      oacc = __builtin_amdgcn_mfma_f32_16x16x32_bf16(
          op[(q * 64 + mt * 16 + col) * 4 + grp], nb[q], oacc, 0, 0, 0);
#pragma unroll
    for (int r = 0; r < 4; ++r)
      out[(mt * 16 + grp * 4 + r) * HW + p] = oacc[r];
  }
}

extern "C" void kernel_launch(void* const* d_in, const int* in_sizes, int n_in,
                              void* d_out, int out_size, void* d_ws, size_t ws_size,
                              hipStream_t stream) {
  const float* rgb  = (const float*)d_in[0];
  const float* ev   = (const float*)d_in[1];
  const float* cw   = (const float*)d_in[2];
  const float* g    = (const float*)d_in[3];
  const float* b    = (const float*)d_in[4];
  const float* w3   = (const float*)d_in[5];
  const float* df2  = (const float*)d_in[6];
  const float* spw  = (const float*)d_in[7];
  const float* outw = (const float*)d_in[8];
  float* out = (float*)d_out;
  char* wsb = (char*)d_ws;

  const size_t MB = 1u << 20;
  short* featT_rgb = (short*)(wsb);             // 4 MB
  short* featT_ev  = (short*)(wsb + 4 * MB);    // 4 MB
  short* rT_rgb    = (short*)(wsb + 8 * MB);    // 4 MB
  short* rT_ev     = (short*)(wsb + 12 * MB);   // 4 MB
  short* enT_rgb   = (short*)(wsb + 16 * MB);   // 4 MB
  short* enT_ev    = (short*)(wsb + 20 * MB);   // 4 MB
  short* xT_rgb    = (short*)(wsb + 24 * MB);   // 2 MB
  short* xT_ev     = (short*)(wsb + 26 * MB);   // 2 MB
  short* df2p      = (short*)(wsb + 28 * MB);   // 1 MB
  short* w3p       = (short*)(wsb + 29 * MB);   // 288 KB
  short* cwp       = (short*)(wsb + 30 * MB);   // 16 KB
  short* spwp      = (short*)(wsb + 31 * MB);   // 32 KB
  short* outwp     = (short*)(wsb + 32 * MB);   // 16 KB

  hipLaunchKernelGGL(k_prep_x, dim3(64, 1, 2), dim3(256), 0, stream,
                     rgb, ev, xT_rgb, xT_ev);
  hipLaunchKernelGGL(k_prep_cw, dim3(32), dim3(256), 0, stream, cw, cwp);
  hipLaunchKernelGGL(k_prep_w3, dim3(576), dim3(256), 0, stream, w3, w3p);
  hipLaunchKernelGGL(k_prep_df2, dim3(2048), dim3(256), 0, stream, df2, df2p);
  hipLaunchKernelGGL(k_prep_spw, dim3(64), dim3(256), 0, stream, spw, spwp);
  hipLaunchKernelGGL(k_prep_outw, dim3(32), dim3(256), 0, stream, outw, outwp);
  hipLaunchKernelGGL(k_feat_mfma, dim3(256, 1, 2), dim3(256), 0, stream,
                     xT_rgb, xT_ev, cwp, g, b, featT_rgb, featT_ev);
  hipLaunchKernelGGL(k_conv3_v2, dim3(256, 1, 2), dim3(256), 0, stream,
                     featT_rgb, featT_ev, w3p, rT_rgb, rT_ev);
  hipLaunchKernelGGL(k_filt_v5, dim3(64, 16, 2), dim3(256), 0, stream,
                     featT_rgb, featT_ev, rT_rgb, rT_ev, df2p, enT_rgb, enT_ev);
  hipLaunchKernelGGL(k_post, dim3(256), dim3(256), 0, stream,
                     enT_rgb, enT_ev, featT_rgb, spwp, outwp, g, b, out);
}

// Round 7
// 124.442 us; speedup vs baseline: 15.2590x; 1.2597x over previous
//
#include <hip/hip_runtime.h>
#include <math.h>

#define HW 16384
#define WD 128
#define HD 128
#define CIN 64
#define CH 128
#define EPSV 1e-5f

typedef __attribute__((ext_vector_type(8))) short short8;
typedef __attribute__((ext_vector_type(4))) short short4v;
typedef __attribute__((ext_vector_type(4))) float f32x4;

__device__ __forceinline__ short f2bf(float x) {
  unsigned u = __float_as_uint(x);
  u += 0x7FFFu + ((u >> 16) & 1u);   // RNE
  return (short)(u >> 16);
}
__device__ __forceinline__ float bf2f(short x) {
  return __uint_as_float(((unsigned)(unsigned short)x) << 16);
}

// ---------------------------------------------------------------------------
// Prep: x [64][HW] fp32 -> xT [p][64] bf16
// ---------------------------------------------------------------------------
__global__ __launch_bounds__(256) void k_prep_x(const float* __restrict__ rgb,
                                                const float* __restrict__ ev,
                                                short* __restrict__ xT_rgb,
                                                short* __restrict__ xT_ev) {
  const float* x = blockIdx.z ? ev : rgb;
  short* xT = blockIdx.z ? xT_ev : xT_rgb;
  int p = blockIdx.x * 256 + threadIdx.x;
#pragma unroll
  for (int cb = 0; cb < 8; ++cb) {
    short8 v;
#pragma unroll
    for (int j = 0; j < 8; ++j) v[j] = f2bf(x[(cb * 8 + j) * HW + p]);
    *(short8*)(xT + p * CIN + cb * 8) = v;
  }
}

// ---------------------------------------------------------------------------
// Weight preps -> A-frag layout [q][m][grp4][j8] bf16
// ---------------------------------------------------------------------------
__global__ __launch_bounds__(256) void k_prep_cw(const float* __restrict__ cw,
                                                 short* __restrict__ cwp) {
  int idx = blockIdx.x * 256 + threadIdx.x;  // 8192: q2 x m128
  int j = idx & 7, grp = (idx >> 3) & 3, m = (idx >> 5) & 127, q = idx >> 12;
  cwp[idx] = f2bf(cw[m * CIN + q * 32 + grp * 8 + j]);
}

__global__ __launch_bounds__(256) void k_prep_w3(const float* __restrict__ w3,
                                                 short* __restrict__ w3p) {
  int idx = blockIdx.x * 256 + threadIdx.x;  // 147456: ks36 x m128
  int j = idx & 7, grp = (idx >> 3) & 3, m = (idx >> 5) & 127, ks = idx >> 12;
  int tap = ks >> 2, q = ks & 3;
  int c = q * 32 + grp * 8 + j;
  w3p[idx] = f2bf(w3[(m * CH + c) * 9 + tap]);
}

// df2 [3200][128] fp32 -> df2p [c][slot'][8] bf16, slot' = t*16 + (k8 ^ (t&7))
// (XOR swizzle baked into the SOURCE so the LDS copy stays linear and the
//  in-kernel ds_read at t*16 + ((q*4+grp)^(t&7)) is bank-spread; rule #21)
__global__ __launch_bounds__(256) void k_prep_df2(const float* __restrict__ df2,
                                                  short* __restrict__ df2p) {
  int idx = blockIdx.x * 256 + threadIdx.x;  // 524288
  int j = idx & 7;
  int slotp = (idx >> 3) & 511;
  int c = idx >> 12;
  int t = slotp >> 4, k8l = slotp & 15;
  int k8 = k8l ^ (t & 7);
  float v = (t < 25) ? df2[(c * 25 + t) * CH + k8 * 8 + j] : 0.f;
  df2p[idx] = f2bf(v);
}

__global__ __launch_bounds__(256) void k_prep_spw(const float* __restrict__ spw,
                                                  short* __restrict__ spwp) {
  int idx = blockIdx.x * 256 + threadIdx.x;  // 16384: q4 x m128
  int j = idx & 7, grp = (idx >> 3) & 3, m = (idx >> 5) & 127, q = idx >> 12;
  spwp[idx] = f2bf(spw[m * CH + q * 32 + grp * 8 + j]);
}

__global__ __launch_bounds__(256) void k_prep_outw(const float* __restrict__ outw,
                                                   short* __restrict__ outwp) {
  int idx = blockIdx.x * 256 + threadIdx.x;  // 8192: q4 x m64
  int j = idx & 7, grp = (idx >> 3) & 3, m = (idx >> 5) & 63, q = idx >> 11;
  outwp[idx] = f2bf(outw[m * CH + q * 32 + grp * 8 + j]);
}

// ---------------------------------------------------------------------------
// Kernel 1 (MFMA): featT = bf16(LN_c(conv1x1(x, cw)))  [p][128]
// ---------------------------------------------------------------------------
__global__ __launch_bounds__(256) void k_feat_mfma(
    const short* __restrict__ xT_rgb, const short* __restrict__ xT_ev,
    const short* __restrict__ cwp, const float* __restrict__ g,
    const float* __restrict__ b,
    short* __restrict__ featT_rgb, short* __restrict__ featT_ev) {
  __shared__ float sg[CH], sb[CH];
  int tid = threadIdx.x;
  if (tid < CH) { sg[tid] = g[tid]; sb[tid] = b[tid]; }
  __syncthreads();
  const short* xT = blockIdx.z ? xT_ev : xT_rgb;
  short* featT = blockIdx.z ? featT_ev : featT_rgb;
  int wave = tid >> 6, lane = tid & 63, col = lane & 15, grp = lane >> 4;
  int p = blockIdx.x * 64 + wave * 16 + col;

  const short8* bp = (const short8*)(xT + p * CIN);
  short8 bq0 = bp[grp], bq1 = bp[4 + grp];
  const short8* ap = (const short8*)cwp;

  f32x4 acc[8];
#pragma unroll
  for (int mt = 0; mt < 8; ++mt) {
    acc[mt] = (f32x4){0.f, 0.f, 0.f, 0.f};
    short8 a0 = ap[(0 * 128 + mt * 16 + col) * 4 + grp];
    short8 a1 = ap[(1 * 128 + mt * 16 + col) * 4 + grp];
    acc[mt] = __builtin_amdgcn_mfma_f32_16x16x32_bf16(a0, bq0, acc[mt], 0, 0, 0);
    acc[mt] = __builtin_amdgcn_mfma_f32_16x16x32_bf16(a1, bq1, acc[mt], 0, 0, 0);
  }
  float s = 0.f, s2 = 0.f;
#pragma unroll
  for (int mt = 0; mt < 8; ++mt)
#pragma unroll
    for (int r = 0; r < 4; ++r) { float v = acc[mt][r]; s += v; s2 += v * v; }
  s += __shfl_xor(s, 16);  s += __shfl_xor(s, 32);
  s2 += __shfl_xor(s2, 16); s2 += __shfl_xor(s2, 32);
  float mean = s * (1.f / CH);
  float var = s2 * (1.f / CH) - mean * mean;
  float rinv = rsqrtf(var + EPSV);
#pragma unroll
  for (int mt = 0; mt < 8; ++mt) {
    short4v fv;
#pragma unroll
    for (int r = 0; r < 4; ++r) {
      int m = mt * 16 + grp * 4 + r;
      fv[r] = f2bf((acc[mt][r] - mean) * rinv * sg[m] + sb[m]);
    }
    *(short4v*)(featT + p * CH + mt * 16 + grp * 4) = fv;
  }
}

// ---------------------------------------------------------------------------
// Kernel 2 (MFMA): rT = bf16(relu(conv3x3(featT, df1_w))), implicit im2col.
// ---------------------------------------------------------------------------
__global__ __launch_bounds__(256) void k_conv3_v2(
    const short* __restrict__ featT_rgb, const short* __restrict__ featT_ev,
    const short* __restrict__ w3p,
    short* __restrict__ rT_rgb, short* __restrict__ rT_ev) {
  const short* featT = blockIdx.z ? featT_ev : featT_rgb;
  short* rT = blockIdx.z ? rT_ev : rT_rgb;
  int tid = threadIdx.x, wave = tid >> 6, lane = tid & 63;
  int col = lane & 15, grp = lane >> 4;
  int mh = wave & 1;                       // m-half
  int ty = (blockIdx.x >> 3) * 4 + (wave >> 1) * 2;
  int tx = (blockIdx.x & 7) * 16;
  int x = tx + col;

  f32x4 acc[2][4];
#pragma unroll
  for (int s = 0; s < 2; ++s)
#pragma unroll
    for (int mt = 0; mt < 4; ++mt) acc[s][mt] = (f32x4){0.f, 0.f, 0.f, 0.f};

  const short8* ap = (const short8*)w3p;
  for (int ks = 0; ks < 36; ++ks) {
    int tap = ks >> 2, q = ks & 3;
    int dy = tap / 3 - 1, dx = tap % 3 - 1;
    int xs = x + dx;
    bool xok = (unsigned)xs < (unsigned)WD;
    int y0 = ty + dy, y1 = ty + 1 + dy;
    short8 b0 = {0, 0, 0, 0, 0, 0, 0, 0}, b1 = {0, 0, 0, 0, 0, 0, 0, 0};
    if (xok && (unsigned)y0 < (unsigned)HD)
      b0 = *(const short8*)(featT + (y0 * WD + xs) * CH + q * 32 + grp * 8);
    if (xok && (unsigned)y1 < (unsigned)HD)
      b1 = *(const short8*)(featT + (y1 * WD + xs) * CH + q * 32 + grp * 8);
#pragma unroll
    for (int mt = 0; mt < 4; ++mt) {
      short8 a = ap[(ks * 128 + (mh * 4 + mt) * 16 + col) * 4 + grp];
      acc[0][mt] = __builtin_amdgcn_mfma_f32_16x16x32_bf16(a, b0, acc[0][mt], 0, 0, 0);
      acc[1][mt] = __builtin_amdgcn_mfma_f32_16x16x32_bf16(a, b1, acc[1][mt], 0, 0, 0);
    }
  }
#pragma unroll
  for (int s = 0; s < 2; ++s) {
    int p = (ty + s) * WD + x;
#pragma unroll
    for (int mt = 0; mt < 4; ++mt) {
      short4v v;
#pragma unroll
      for (int r = 0; r < 4; ++r) v[r] = f2bf(fmaxf(acc[s][mt][r], 0.f));
      *(short4v*)(rT + p * CH + (mh * 4 + mt) * 16 + grp * 4) = v;
    }
  }
}

// ---------------------------------------------------------------------------
// Kernel 3 v6: fused dynamic-filter gen + 5x5 apply.
// c-chunk 4 (grid.y=32, 4096 blocks, ~3 blocks/CU). df2 A-matrix staged in
// LDS (32 KB, shared by all 4 waves; source pre-swizzled for bank-spread
// ds_read_b128). B-frags (rv, 64 VGPR) pinned resident; A read per-c-half
// from LDS (16 VGPR live) -> total ~140 VGPR, no global loads in c-loop.
// ---------------------------------------------------------------------------
__global__ __launch_bounds__(256, 3) void k_filt_v6(
    const short* __restrict__ featT_rgb, const short* __restrict__ featT_ev,
    const short* __restrict__ rT_rgb, const short* __restrict__ rT_ev,
    const short* __restrict__ df2p,
    short* __restrict__ enT_rgb, short* __restrict__ enT_ev) {
  __shared__ short lsA[4 * 512 * 8];     // 32 KB: 4 c x 512 slots x 16B
  __shared__ float fwv[4 * 400 + 64];    // 6.6 KB feat window + finite tail
  const short* featT = blockIdx.z ? featT_ev : featT_rgb;
  const short* rT = blockIdx.z ? rT_ev : rT_rgb;
  short* enT = blockIdx.z ? enT_ev : enT_rgb;
  int tid = threadIdx.x;
  int wave = tid >> 6, lane = tid & 63;
  int col = lane & 15, grp = lane >> 4;
  int ty0 = (blockIdx.x >> 3) * 16, tx0 = (blockIdx.x & 7) * 16;
  int c0 = blockIdx.y * 4;
  int py0 = ty0 + wave * 4;
  int pxx = tx0 + col;

  // stage df2p chunk (linear copy; swizzle is pre-baked in the source)
  {
    const short8* gsrc = (const short8*)(df2p + (size_t)c0 * 4096);
    short8* lA = (short8*)lsA;
    for (int i = tid; i < 2048; i += 256) lA[i] = gsrc[i];
  }
  // stage zero-padded feat window rows ty0-2..ty0+17, cols tx0-2..tx0+17
  for (int px = tid; px < 400; px += 256) {
    int wr = px / 20, wc = px % 20;
    int y = ty0 + wr - 2, x = tx0 + wc - 2;
    short4v v = {0, 0, 0, 0};
    if ((unsigned)y < (unsigned)HD && (unsigned)x < (unsigned)WD)
      v = *(const short4v*)(featT + (y * WD + x) * CH + c0);
#pragma unroll
    for (int ci = 0; ci < 4; ++ci) fwv[ci * 400 + px] = bf2f(v[ci]);
  }
  if (tid < 64) fwv[4 * 400 + tid] = 0.f;   // finite tail for tap>=25 reads

  // B fragments, resident for whole c-loop (pinned)
  short8 rv[4][4];
#pragma unroll
  for (int s = 0; s < 4; ++s) {
    const short8* bp = (const short8*)(rT + ((py0 + s) * WD + pxx) * CH);
#pragma unroll
    for (int q = 0; q < 4; ++q) rv[s][q] = bp[q * 4 + grp];
  }
#pragma unroll
  for (int s = 0; s < 4; ++s)
#pragma unroll
    for (int q = 0; q < 4; ++q) asm volatile("" :: "v"(rv[s][q]));

  // epilogue LDS indices (add s*20 at use)
  int idx0[4], idx1[4];
#pragma unroll
  for (int r = 0; r < 4; ++r) {
    int tap0 = grp * 4 + r;
    int tap1 = 16 + grp * 4 + r;
    idx0[r] = (wave * 4 + tap0 / 5) * 20 + col + tap0 % 5;
    idx1[r] = (wave * 4 + tap1 / 5) * 20 + col + tap1 % 5;
  }
  __syncthreads();

  const short8* lA8 = (const short8*)lsA;
  int sw = (grp << 2) ^ (col & 7);   // swizzled k8-low bits base (q=0)
  // store pointer: all 64 lanes store row (py0+grp), col pxx, 4 c as short4v
  short* stp = enT + ((py0 + grp) * WD + pxx) * CH + c0;
  short4v sv;

#pragma unroll
  for (int c = 0; c < 4; ++c) {
    int base0 = c * 512 + col * 16;     // t = col
    int base1 = base0 + 256;            // t = col + 16
    short8 a[4];
    f32x4 acc0[4], acc1[4];
    // m-tile 0 (taps 0..15)
#pragma unroll
    for (int q = 0; q < 4; ++q) a[q] = lA8[base0 + ((q << 2) ^ sw ^ (grp << 2) ^ grp) ];
    // note: ((q*4+grp) ^ (col&7)) = (q<<2 | grp) ^ (col&7); grp in low bits
#pragma unroll
    for (int q = 0; q < 4; ++q) a[q] = lA8[base0 + (((q << 2) | grp) ^ (col & 7))];
#pragma unroll
    for (int s = 0; s < 4; ++s) {
      acc0[s] = (f32x4){0.f, 0.f, 0.f, 0.f};
#pragma unroll
      for (int q = 0; q < 4; ++q)
        acc0[s] = __builtin_amdgcn_mfma_f32_16x16x32_bf16(a[q], rv[s][q], acc0[s], 0, 0, 0);
    }
    // m-tile 1 (taps 16..31)
#pragma unroll
    for (int q = 0; q < 4; ++q) a[q] = lA8[base1 + (((q << 2) | grp) ^ (col & 7))];
#pragma unroll
    for (int s = 0; s < 4; ++s) {
      acc1[s] = (f32x4){0.f, 0.f, 0.f, 0.f};
#pragma unroll
      for (int q = 0; q < 4; ++q)
        acc1[s] = __builtin_amdgcn_mfma_f32_16x16x32_bf16(a[q], rv[s][q], acc1[s], 0, 0, 0);
    }
    // batched epilogue
    const float* fwc = fwv + c * 400;
    float part[4];
#pragma unroll
    for (int s = 0; s < 4; ++s) {
      float p = 0.f;
#pragma unroll
      for (int r = 0; r < 4; ++r) {
        p += fwc[idx0[r] + s * 20] * acc0[s][r];
        p += fwc[idx1[r] + s * 20] * acc1[s][r];
      }
      part[s] = p;
    }
#pragma unroll
    for (int s = 0; s < 4; ++s) part[s] += __shfl_xor(part[s], 16);
#pragma unroll
    for (int s = 0; s < 4; ++s) part[s] += __shfl_xor(part[s], 32);
    float val = (grp == 0) ? part[0] : (grp == 1) ? part[1]
              : (grp == 2) ? part[2] : part[3];
    sv[c] = f2bf(val);
  }
  *(short4v*)stp = sv;
}

// ---------------------------------------------------------------------------
// Kernel 4 (fused k_fuse + LN + k_out, all MFMA):
// ---------------------------------------------------------------------------
__global__ __launch_bounds__(256) void k_post(
    const short* __restrict__ enT_rgb, const short* __restrict__ enT_ev,
    const short* __restrict__ featT_rgb,
    const short* __restrict__ spwp, const short* __restrict__ outwp,
    const float* __restrict__ g, const float* __restrict__ b,
    float* __restrict__ out) {
  __shared__ short nlds[4][16 * 136];   // 17.4 KB
  __shared__ float sg[CH], sb[CH];
  int tid = threadIdx.x;
  if (tid < CH) { sg[tid] = g[tid]; sb[tid] = b[tid]; }
  __syncthreads();
  int wave = tid >> 6, lane = tid & 63, col = lane & 15, grp = lane >> 4;
  int p = blockIdx.x * 64 + wave * 16 + col;

  // gate GEMM: z[128 o][16 px] = sp_w @ en_ev
  const short8* bp = (const short8*)(enT_ev + p * CH);
  short8 bq[4];
#pragma unroll
  for (int q = 0; q < 4; ++q) bq[q] = bp[q * 4 + grp];
  const short8* ap = (const short8*)spwp;
  f32x4 z[8];
#pragma unroll
  for (int mt = 0; mt < 8; ++mt) {
    z[mt] = (f32x4){0.f, 0.f, 0.f, 0.f};
#pragma unroll
    for (int q = 0; q < 4; ++q)
      z[mt] = __builtin_amdgcn_mfma_f32_16x16x32_bf16(
          ap[(q * 128 + mt * 16 + col) * 4 + grp], bq[q], z[mt], 0, 0, 0);
  }

  // fused + LN stats
  const short4v* er = (const short4v*)(enT_rgb + p * CH);
  const short4v* fr = (const short4v*)(featT_rgb + p * CH);
  float fused[8][4];
  float s = 0.f, s2 = 0.f;
#pragma unroll
  for (int mt = 0; mt < 8; ++mt) {
    short4v e4 = er[mt * 4 + grp];
    short4v f4 = fr[mt * 4 + grp];
#pragma unroll
    for (int r = 0; r < 4; ++r) {
      float sig = 1.f / (1.f + __expf(-z[mt][r]));
      float f = bf2f(e4[r]) * (1.f + sig) + bf2f(f4[r]);
      fused[mt][r] = f; s += f; s2 += f * f;
    }
  }
  s += __shfl_xor(s, 16);  s += __shfl_xor(s, 32);
  s2 += __shfl_xor(s2, 16); s2 += __shfl_xor(s2, 32);
  float mean = s * (1.f / CH);
  float var = s2 * (1.f / CH) - mean * mean;
  float rinv = rsqrtf(var + EPSV);

  // normalize -> bf16 -> LDS [px][o] (stride 136)
  short* nl = &nlds[wave][0];
#pragma unroll
  for (int mt = 0; mt < 8; ++mt) {
    short4v nv;
#pragma unroll
    for (int r = 0; r < 4; ++r) {
      int o = mt * 16 + grp * 4 + r;
      nv[r] = f2bf((fused[mt][r] - mean) * rinv * sg[o] + sb[o]);
    }
    *(short4v*)(nl + col * 136 + mt * 16 + grp * 4) = nv;
  }

  // out GEMM: out[64 o][16 px] = out_w @ norm
  short8 nb[4];
#pragma unroll
  for (int q = 0; q < 4; ++q)
    nb[q] = *(const short8*)(nl + col * 136 + q * 32 + grp * 8);
  const short8* op = (const short8*)outwp;
#pragma unroll
  for (int mt = 0; mt < 4; ++mt) {
    f32x4 oacc = {0.f, 0.f, 0.f, 0.f};
#pragma unroll
    for (int q = 0; q < 4; ++q)
      oacc = __builtin_amdgcn_mfma_f32_16x16x32_bf16(
          op[(q * 64 + mt * 16 + col) * 4 + grp], nb[q], oacc, 0, 0, 0);
#pragma unroll
    for (int r = 0; r < 4; ++r)
      out[(mt * 16 + grp * 4 + r) * HW + p] = oacc[r];
  }
}

extern "C" void kernel_launch(void* const* d_in, const int* in_sizes, int n_in,
                              void* d_out, int out_size, void* d_ws, size_t ws_size,
                              hipStream_t stream) {
  const float* rgb  = (const float*)d_in[0];
  const float* ev   = (const float*)d_in[1];
  const float* cw   = (const float*)d_in[2];
  const float* g    = (const float*)d_in[3];
  const float* b    = (const float*)d_in[4];
  const float* w3   = (const float*)d_in[5];
  const float* df2  = (const float*)d_in[6];
  const float* spw  = (const float*)d_in[7];
  const float* outw = (const float*)d_in[8];
  float* out = (float*)d_out;
  char* wsb = (char*)d_ws;

  const size_t MB = 1u << 20;
  short* featT_rgb = (short*)(wsb);             // 4 MB
  short* featT_ev  = (short*)(wsb + 4 * MB);    // 4 MB
  short* rT_rgb    = (short*)(wsb + 8 * MB);    // 4 MB
  short* rT_ev     = (short*)(wsb + 12 * MB);   // 4 MB
  short* enT_rgb   = (short*)(wsb + 16 * MB);   // 4 MB
  short* enT_ev    = (short*)(wsb + 20 * MB);   // 4 MB
  short* xT_rgb    = (short*)(wsb + 24 * MB);   // 2 MB
  short* xT_ev     = (short*)(wsb + 26 * MB);   // 2 MB
  short* df2p      = (short*)(wsb + 28 * MB);   // 1 MB
  short* w3p       = (short*)(wsb + 29 * MB);   // 288 KB
  short* cwp       = (short*)(wsb + 30 * MB);   // 16 KB
  short* spwp      = (short*)(wsb + 31 * MB);   // 32 KB
  short* outwp     = (short*)(wsb + 32 * MB);   // 16 KB

  hipLaunchKernelGGL(k_prep_x, dim3(64, 1, 2), dim3(256), 0, stream,
                     rgb, ev, xT_rgb, xT_ev);
  hipLaunchKernelGGL(k_prep_cw, dim3(32), dim3(256), 0, stream, cw, cwp);
  hipLaunchKernelGGL(k_prep_w3, dim3(576), dim3(256), 0, stream, w3, w3p);
  hipLaunchKernelGGL(k_prep_df2, dim3(2048), dim3(256), 0, stream, df2, df2p);
  hipLaunchKernelGGL(k_prep_spw, dim3(64), dim3(256), 0, stream, spw, spwp);
  hipLaunchKernelGGL(k_prep_outw, dim3(32), dim3(256), 0, stream, outw, outwp);
  hipLaunchKernelGGL(k_feat_mfma, dim3(256, 1, 2), dim3(256), 0, stream,
                     xT_rgb, xT_ev, cwp, g, b, featT_rgb, featT_ev);
  hipLaunchKernelGGL(k_conv3_v2, dim3(256, 1, 2), dim3(256), 0, stream,
                     featT_rgb, featT_ev, w3p, rT_rgb, rT_ev);
  hipLaunchKernelGGL(k_filt_v6, dim3(64, 32, 2), dim3(256), 0, stream,
                     featT_rgb, featT_ev, rT_rgb, rT_ev, df2p, enT_rgb, enT_ev);
  hipLaunchKernelGGL(k_post, dim3(256), dim3(256), 0, stream,
                     enT_rgb, enT_ev, featT_rgb, spwp, outwp, g, b, out);
}